// Round 1
// baseline (198.835 us; speedup 1.0000x reference)
//
#include <hip/hip_runtime.h>
#include <math.h>

#define N_WIRES 12
#define QDIM 4096        // 2^12
#define NQL 2

struct cplx { float r, i; };
__device__ __forceinline__ cplx cmul(cplx a, cplx b){ return {a.r*b.r - a.i*b.i, a.r*b.i + a.i*b.r}; }
__device__ __forceinline__ cplx cadd(cplx a, cplx b){ return {a.r+b.r, a.i+b.i}; }

// ---------------------------------------------------------------------------
// Kernel 1: fold the two TT cores into a single matrix
//   Wt[k][o], k = i*32+j (0..1023), o = p*9+r (0..71)
//   Wt[k][o] = sum_q core0[0,i,p,q] * core1[q,j,r,0]
// ---------------------------------------------------------------------------
__global__ __launch_bounds__(256) void build_w_kernel(
    const float* __restrict__ core0,   // (1,32,8,16)
    const float* __restrict__ core1,   // (16,32,9,1)
    float* __restrict__ Wt) {          // (1024,72)
  int idx = blockIdx.x * 256 + threadIdx.x;   // 0..73727
  int k = idx / 72;
  int o = idx - k * 72;
  int i = k >> 5, j = k & 31;
  int p = o / 9, r = o - p * 9;
  float acc = 0.f;
#pragma unroll
  for (int q = 0; q < 16; ++q) {
    acc += core0[(i * 8 + p) * 16 + q] * core1[(q * 32 + j) * 9 + r];
  }
  Wt[idx] = acc;
}

// ---------------------------------------------------------------------------
// Kernel 2: per-batch-element fused TT-dot + 12-qubit statevector sim
//   one block (256 threads) per batch row; state in LDS
// ---------------------------------------------------------------------------
__global__ __launch_bounds__(256) void vqc_kernel(
    const float* __restrict__ x,        // (2048,1024)
    const float* __restrict__ Wt,       // (1024,72)
    const float* __restrict__ tt_bias,  // (72,)
    const float* __restrict__ gang,     // (2,12,3)
    float* __restrict__ out) {          // (2048,12)
  const int b = blockIdx.x;
  const int t = threadIdx.x;

  __shared__ float xrow[1024];
  __shared__ float sre[QDIM];
  __shared__ float sim_[QDIM];
  __shared__ float tt[72];
  __shared__ float part[216];
  __shared__ float Ure[24][4];
  __shared__ float Uim[24][4];
  __shared__ float ampc[N_WIRES], amps[N_WIRES];

  // --- load x row (coalesced float4) ---
  ((float4*)xrow)[t] = ((const float4*)(x + (size_t)b * 1024))[t];
  __syncthreads();

  // --- TT contraction: tt[o] = sum_j xrow[j] * Wt[j][o] ---
  if (t < 216) {
    int o = t % 72, seg = t / 72;
    int j0 = seg * 342;
    int j1 = (seg == 2) ? 1024 : j0 + 342;
    float acc0 = 0.f, acc1 = 0.f;
    int j = j0;
    for (; j + 1 < j1; j += 2) {
      acc0 += xrow[j]     * Wt[j * 72 + o];
      acc1 += xrow[j + 1] * Wt[(j + 1) * 72 + o];
    }
    if (j < j1) acc0 += xrow[j] * Wt[j * 72 + o];
    part[t] = acc0 + acc1;
  }
  __syncthreads();
  if (t < 72) tt[t] = part[t] + part[t + 72] + part[t + 144] + tt_bias[t];
  __syncthreads();

  // --- build the 24 single-qubit unitaries: U = Rz(a2) Ry(a1) Rx(a0) ---
  if (t < 24) {
    int k = t / N_WIRES, w = t - k * N_WIRES;
    float a0 = gang[t * 3 + 0] + tt[k * 36 + w * 3 + 0];
    float a1 = gang[t * 3 + 1] + tt[k * 36 + w * 3 + 1];
    float a2 = gang[t * 3 + 2] + tt[k * 36 + w * 3 + 2];
    float cx = cosf(0.5f * a0), sx = sinf(0.5f * a0);
    float cy = cosf(0.5f * a1), sy = sinf(0.5f * a1);
    float cz = cosf(0.5f * a2), sz = sinf(0.5f * a2);
    // Rx
    cplx Rx[2][2] = {{{cx, 0.f}, {0.f, -sx}}, {{0.f, -sx}, {cx, 0.f}}};
    // Ry
    cplx Ry[2][2] = {{{cy, 0.f}, {-sy, 0.f}}, {{sy, 0.f}, {cy, 0.f}}};
    // Rz
    cplx ez  = {cz, -sz};
    cplx ezc = {cz,  sz};
    cplx M[2][2];   // Ry @ Rx
#pragma unroll
    for (int a = 0; a < 2; ++a)
#pragma unroll
      for (int c = 0; c < 2; ++c)
        M[a][c] = cadd(cmul(Ry[a][0], Rx[0][c]), cmul(Ry[a][1], Rx[1][c]));
    cplx U00 = cmul(ez,  M[0][0]);
    cplx U01 = cmul(ez,  M[0][1]);
    cplx U10 = cmul(ezc, M[1][0]);
    cplx U11 = cmul(ezc, M[1][1]);
    Ure[t][0] = U00.r; Uim[t][0] = U00.i;
    Ure[t][1] = U01.r; Uim[t][1] = U01.i;
    Ure[t][2] = U10.r; Uim[t][2] = U10.i;
    Ure[t][3] = U11.r; Uim[t][3] = U11.i;
  }
  if (t < N_WIRES) {
    float e = xrow[t] * 0.5f;
    ampc[t] = cosf(e);
    amps[t] = sinf(e);
  }
  __syncthreads();

  // --- product-state init: state[idx] = prod_w amp[w][bit_{11-w}(idx)] ---
#pragma unroll
  for (int rcnt = 0; rcnt < 16; ++rcnt) {
    int idx = t * 16 + rcnt;
    float pr = 1.f;
#pragma unroll
    for (int w = 0; w < N_WIRES; ++w) {
      int bit = (idx >> (11 - w)) & 1;
      pr *= bit ? amps[w] : ampc[w];
    }
    sre[idx] = pr;
    sim_[idx] = 0.f;
  }
  __syncthreads();

  // --- 2 layers of gates + CNOT ring ---
  for (int k = 0; k < NQL; ++k) {
    // 12 single-qubit gates
    for (int w = 0; w < N_WIRES; ++w) {
      int g = k * N_WIRES + w;
      int s = 1 << (11 - w);
      float u00r = Ure[g][0], u00i = Uim[g][0];
      float u01r = Ure[g][1], u01i = Uim[g][1];
      float u10r = Ure[g][2], u10i = Uim[g][2];
      float u11r = Ure[g][3], u11i = Uim[g][3];
#pragma unroll
      for (int pp = 0; pp < 8; ++pp) {
        int p = t + pp * 256;                       // 0..2047
        int i0 = ((p & ~(s - 1)) << 1) | (p & (s - 1));
        int i1 = i0 + s;
        float ar = sre[i0], ai = sim_[i0];
        float br = sre[i1], bi = sim_[i1];
        sre[i0] = u00r * ar - u00i * ai + u01r * br - u01i * bi;
        sim_[i0] = u00r * ai + u00i * ar + u01r * bi + u01i * br;
        sre[i1] = u10r * ar - u10i * ai + u11r * br - u11i * bi;
        sim_[i1] = u10r * ai + u10i * ar + u11r * bi + u11i * br;
      }
      __syncthreads();
    }
    // CNOT ring: (0,1),(1,2),...,(10,11),(11,0)
    for (int c = 0; c < N_WIRES; ++c) {
      int ctrl = c;
      int tgt  = (c + 1) % N_WIRES;
      int pc = 11 - ctrl, pt = 11 - tgt;   // bit positions
      int lo = pc < pt ? pc : pt;
      int hi = pc < pt ? pt : pc;
#pragma unroll
      for (int pp = 0; pp < 4; ++pp) {
        int q = t + pp * 256;                       // 0..1023 (10 free bits)
        int t1 = q & ((1 << lo) - 1);
        int rest = q >> lo;
        int nmid = hi - lo - 1;
        int t2 = rest & ((1 << nmid) - 1);
        int t3 = rest >> nmid;
        int idx = t1 | (t2 << (lo + 1)) | (t3 << (hi + 1)) | (1 << pc); // bit pt = 0
        int jdx = idx ^ (1 << pt);
        float r0 = sre[idx], i0v = sim_[idx];
        sre[idx] = sre[jdx]; sim_[idx] = sim_[jdx];
        sre[jdx] = r0;       sim_[jdx] = i0v;
      }
      __syncthreads();
    }
  }

  // --- measurement: out[b][w] = sum_idx |amp|^2 * (1 - 2*bit_{11-w}(idx)) ---
  float acc[N_WIRES];
#pragma unroll
  for (int w = 0; w < N_WIRES; ++w) acc[w] = 0.f;
#pragma unroll
  for (int rcnt = 0; rcnt < 16; ++rcnt) {
    int idx = t * 16 + rcnt;
    float pr = sre[idx] * sre[idx] + sim_[idx] * sim_[idx];
#pragma unroll
    for (int w = 0; w < N_WIRES; ++w) {
      acc[w] += ((idx >> (11 - w)) & 1) ? -pr : pr;
    }
  }
  // wave reduce (64 lanes), then cross-wave via LDS
#pragma unroll
  for (int w = 0; w < N_WIRES; ++w) {
    float v = acc[w];
    for (int off = 32; off > 0; off >>= 1) v += __shfl_down(v, off, 64);
    if ((t & 63) == 0) part[(t >> 6) * N_WIRES + w] = v;
  }
  __syncthreads();
  if (t < N_WIRES) {
    out[(size_t)b * N_WIRES + t] =
        part[t] + part[N_WIRES + t] + part[2 * N_WIRES + t] + part[3 * N_WIRES + t];
  }
}

// ---------------------------------------------------------------------------
extern "C" void kernel_launch(void* const* d_in, const int* in_sizes, int n_in,
                              void* d_out, int out_size, void* d_ws, size_t ws_size,
                              hipStream_t stream) {
  const float* x       = (const float*)d_in[0];
  const float* core0   = (const float*)d_in[1];
  const float* core1   = (const float*)d_in[2];
  const float* tt_bias = (const float*)d_in[3];
  const float* gang    = (const float*)d_in[4];
  float* out = (float*)d_out;
  float* Wt  = (float*)d_ws;           // 73728 floats = 288 KiB scratch

  const int bsz = in_sizes[0] / 1024;  // 2048

  build_w_kernel<<<288, 256, 0, stream>>>(core0, core1, Wt);
  vqc_kernel<<<bsz, 256, 0, stream>>>(x, Wt, tt_bias, gang, out);
}

// Round 2
// 128.986 us; speedup vs baseline: 1.5415x; 1.5415x over previous
//
#include <hip/hip_runtime.h>
#include <math.h>

#define N_WIRES 12

// ---------------------------------------------------------------------------
// compile-time parity helper (folds for constant args in unrolled loops)
// ---------------------------------------------------------------------------
__host__ __device__ constexpr int parity12(int x) {
  x ^= x >> 8; x ^= x >> 4; x ^= x >> 2; x ^= x >> 1;
  return x & 1;
}

// ---------------------------------------------------------------------------
// Kernel 1: fold the two TT cores into a single matrix
//   Wt[k][o], k = i*32+j (0..1023), o = p*9+r (0..71)
// ---------------------------------------------------------------------------
__global__ __launch_bounds__(256) void build_w_kernel(
    const float* __restrict__ core0,   // (1,32,8,16)
    const float* __restrict__ core1,   // (16,32,9,1)
    float* __restrict__ Wt) {          // (1024,72)
  int idx = blockIdx.x * 256 + threadIdx.x;   // 0..73727
  int k = idx / 72;
  int o = idx - k * 72;
  int i = k >> 5, j = k & 31;
  int p = o / 9, r = o - p * 9;
  float acc = 0.f;
#pragma unroll
  for (int q = 0; q < 16; ++q) {
    acc += core0[(i * 8 + p) * 16 + q] * core1[(q * 32 + j) * 9 + r];
  }
  Wt[idx] = acc;
}

// ---------------------------------------------------------------------------
// Generic single-qubit gate on register-resident state.
//   Physical index p = (t<<4) | r   (t = thread 0..255, r = register 0..15)
//   Pairing: p <-> p ^ MASK.  Branch bit ("a" vs "b") = parity(ROW & p).
//   MASK bits 0-3 -> register xor; bits 4-9 -> lane xor (shfl);
//   bits 10-11 -> wave xor (LDS exchange).
// ---------------------------------------------------------------------------
template <int MASK, int ROW>
__device__ __forceinline__ void apply_gate(
    float vr[16], float vi[16],
    float u00r, float u00i, float u01r, float u01i,
    float u10r, float u10i, float u11r, float u11i,
    float* __restrict__ buf, int t) {
  constexpr int RM = MASK & 15;             // register-bit part
  constexpr int TM = (MASK >> 4) & 0xFF;    // thread-bit part
  constexpr int LM = TM & 63;               // lane-bit part
  constexpr bool LDSX = (TM & 0xC0) != 0;   // crosses waves -> LDS exchange

  // thread-level parity contribution to the branch bit
  const int tpar = __popc(ROW & (t << 4)) & 1;
  // coefficient set P: for amps with compile-time reg-parity 0
  const float aor = tpar ? u11r : u00r, aoi = tpar ? u11i : u00i;
  const float apr = tpar ? u10r : u01r, api = tpar ? u10i : u01i;
  // coefficient set Q: for amps with compile-time reg-parity 1
  const float qor = tpar ? u00r : u11r, qoi = tpar ? u00i : u11i;
  const float qpr = tpar ? u01r : u10r, qpi = tpar ? u01i : u10i;

  if constexpr (LDSX) {
    __syncthreads();                         // protect buf from previous use
#pragma unroll
    for (int r = 0; r < 16; ++r) {
      buf[r * 256 + t] = vr[r];
      buf[4096 + r * 256 + t] = vi[r];
    }
    __syncthreads();
    const int tp = t ^ TM;
#pragma unroll
    for (int r = 0; r < 16; ++r) {
      const int r2 = r ^ RM;
      const float br = buf[r2 * 256 + tp];
      const float bi = buf[4096 + r2 * 256 + tp];
      const float ar = vr[r], ai = vi[r];
      const bool b1 = parity12(ROW & r);
      const float cor = b1 ? qor : aor, coi = b1 ? qoi : aoi;
      const float cpr = b1 ? qpr : apr, cpi = b1 ? qpi : api;
      vr[r] = cor * ar - coi * ai + cpr * br - cpi * bi;
      vi[r] = cor * ai + coi * ar + cpr * bi + cpi * br;
    }
  } else if constexpr (LM != 0 && RM == 0) {
#pragma unroll
    for (int r = 0; r < 16; ++r) {
      const float br = __shfl_xor(vr[r], LM, 64);
      const float bi = __shfl_xor(vi[r], LM, 64);
      const float ar = vr[r], ai = vi[r];
      const bool b1 = parity12(ROW & r);
      const float cor = b1 ? qor : aor, coi = b1 ? qoi : aoi;
      const float cpr = b1 ? qpr : apr, cpi = b1 ? qpi : api;
      vr[r] = cor * ar - coi * ai + cpr * br - cpi * bi;
      vi[r] = cor * ai + coi * ar + cpr * bi + cpi * br;
    }
  } else if constexpr (LM != 0 && RM != 0) {
    // pair (r, r^RM) so no register is read after being overwritten
#pragma unroll
    for (int r = 0; r < 16; ++r) {
      constexpr auto dummy = 0; (void)dummy;
      if (r < (r ^ RM)) {
        const int r2 = r ^ RM;
        const float p1r = __shfl_xor(vr[r2], LM, 64);  // partner for my r
        const float p1i = __shfl_xor(vi[r2], LM, 64);
        const float p2r = __shfl_xor(vr[r], LM, 64);   // partner for my r2
        const float p2i = __shfl_xor(vi[r], LM, 64);
        const float ar = vr[r], ai = vi[r];
        const float br = vr[r2], bi = vi[r2];
        {
          const bool b1 = parity12(ROW & r);
          const float cor = b1 ? qor : aor, coi = b1 ? qoi : aoi;
          const float cpr = b1 ? qpr : apr, cpi = b1 ? qpi : api;
          vr[r] = cor * ar - coi * ai + cpr * p1r - cpi * p1i;
          vi[r] = cor * ai + coi * ar + cpr * p1i + cpi * p1r;
        }
        {
          const bool b1 = parity12(ROW & r2);
          const float cor = b1 ? qor : aor, coi = b1 ? qoi : aoi;
          const float cpr = b1 ? qpr : apr, cpi = b1 ? qpi : api;
          vr[r2] = cor * br - coi * bi + cpr * p2r - cpi * p2i;
          vi[r2] = cor * bi + coi * br + cpr * p2i + cpi * p2r;
        }
      }
    }
  } else {
    // pure register gate: pair (r, r^RM)
#pragma unroll
    for (int r = 0; r < 16; ++r) {
      if (r < (r ^ RM)) {
        const int r2 = r ^ RM;
        const float ar = vr[r], ai = vi[r];
        const float br = vr[r2], bi = vi[r2];
        {
          const bool b1 = parity12(ROW & r);
          const float cor = b1 ? qor : aor, coi = b1 ? qoi : aoi;
          const float cpr = b1 ? qpr : apr, cpi = b1 ? qpi : api;
          vr[r] = cor * ar - coi * ai + cpr * br - cpi * bi;
          vi[r] = cor * ai + coi * ar + cpr * bi + cpi * br;
        }
        {
          const bool b1 = parity12(ROW & r2);
          const float cor = b1 ? qor : aor, coi = b1 ? qoi : aoi;
          const float cpr = b1 ? qpr : apr, cpi = b1 ? qpi : api;
          vr[r2] = cor * br - coi * bi + cpr * ar - cpi * ai;
          vi[r2] = cor * bi + coi * br + cpr * ai + cpi * ar;
        }
      }
    }
  }
}

// ---------------------------------------------------------------------------
// Kernel 2: per-batch-element fused TT-dot + 12-qubit statevector sim.
// State lives in registers (16 complex amps / thread). CNOTs are deferred
// into GF(2) index transforms (precomputed masks below).
// ---------------------------------------------------------------------------
__global__ __launch_bounds__(256) void vqc_kernel(
    const float* __restrict__ x,        // (2048,1024)
    const float* __restrict__ Wt,       // (1024,72)
    const float* __restrict__ tt_bias,  // (72,)
    const float* __restrict__ gang,     // (2,12,3)
    float* __restrict__ out) {          // (2048,12)
  const int b = blockIdx.x;
  const int t = threadIdx.x;

  __shared__ float buf[8192];           // exchange buffer; first 1024 = xrow
  __shared__ float part[216];
  __shared__ float tt[72];
  __shared__ float sUre[24][4];
  __shared__ float sUim[24][4];
  __shared__ float ampc[N_WIRES], amps[N_WIRES];

  float* xrow = buf;

  // --- load x row (coalesced float4) ---
  ((float4*)xrow)[t] = ((const float4*)(x + (size_t)b * 1024))[t];
  __syncthreads();

  // --- TT contraction: tt[o] = sum_j xrow[j] * Wt[j][o] ---
  if (t < 216) {
    int o = t % 72, seg = t / 72;
    int j0 = seg * 342;
    int j1 = (seg == 2) ? 1024 : j0 + 342;
    float acc0 = 0.f, acc1 = 0.f;
    int j = j0;
    for (; j + 1 < j1; j += 2) {
      acc0 += xrow[j]     * Wt[j * 72 + o];
      acc1 += xrow[j + 1] * Wt[(j + 1) * 72 + o];
    }
    if (j < j1) acc0 += xrow[j] * Wt[j * 72 + o];
    part[t] = acc0 + acc1;
  }
  __syncthreads();
  if (t < 72) tt[t] = part[t] + part[t + 72] + part[t + 144] + tt_bias[t];
  __syncthreads();

  // --- build the 24 single-qubit unitaries: U = Rz(a2) Ry(a1) Rx(a0) ---
  if (t < 24) {
    int k = t / N_WIRES, w = t - k * N_WIRES;
    float a0 = gang[t * 3 + 0] + tt[k * 36 + w * 3 + 0];
    float a1 = gang[t * 3 + 1] + tt[k * 36 + w * 3 + 1];
    float a2 = gang[t * 3 + 2] + tt[k * 36 + w * 3 + 2];
    float cx = cosf(0.5f * a0), sx = sinf(0.5f * a0);
    float cy = cosf(0.5f * a1), sy = sinf(0.5f * a1);
    float cz = cosf(0.5f * a2), sz = sinf(0.5f * a2);
    // M = Ry @ Rx  (Rx = [[cx,-i sx],[-i sx,cx]], Ry = [[cy,-sy],[sy,cy]])
    float m00r = cy * cx,  m00i = -(-sy) * -sx;  // cy*cx + (-sy)*(-i sx)? expand below
    // do it explicitly with complex arithmetic:
    // Ry row0 = (cy, 0), (-sy, 0); Ry row1 = (sy,0),(cy,0)
    // Rx col0 = (cx,0),(0,-sx); Rx col1 = (0,-sx),(cx,0)
    // M[0][0] = cy*cx + (-sy)*(0,-sx) = (cy*cx, sy*sx)
    // M[0][1] = cy*(0,-sx) + (-sy)*cx = (-sy*cx, -cy*sx)
    // M[1][0] = sy*cx + cy*(0,-sx)   = (sy*cx, -cy*sx)
    // M[1][1] = sy*(0,-sx) + cy*cx   = (cy*cx, -sy*sx)
    m00r = cy * cx;   m00i = sy * sx;
    float m01r = -sy * cx, m01i = -cy * sx;
    float m10r = sy * cx,  m10i = -cy * sx;
    float m11r = cy * cx,  m11i = -sy * sx;
    // U row0 = ez * M row0, U row1 = ezc * M row1; ez = (cz,-sz), ezc = (cz,sz)
    sUre[t][0] = cz * m00r + sz * m00i;  sUim[t][0] = cz * m00i - sz * m00r;
    sUre[t][1] = cz * m01r + sz * m01i;  sUim[t][1] = cz * m01i - sz * m01r;
    sUre[t][2] = cz * m10r - sz * m10i;  sUim[t][2] = cz * m10i + sz * m10r;
    sUre[t][3] = cz * m11r - sz * m11i;  sUim[t][3] = cz * m11i + sz * m11r;
  }
  if (t < N_WIRES) {
    float e = xrow[t] * 0.5f;
    ampc[t] = cosf(e);
    amps[t] = sinf(e);
  }
  __syncthreads();

  // --- product-state init directly into registers ---
  float vr[16], vi[16];
  {
    float base = 1.f;
#pragma unroll
    for (int w = 0; w < 8; ++w) {
      int bit = (t >> (7 - w)) & 1;       // p bit (11-w) = t bit (7-w)
      base *= bit ? amps[w] : ampc[w];
    }
    const float f8c = ampc[8],  f8s = amps[8];
    const float f9c = ampc[9],  f9s = amps[9];
    const float fAc = ampc[10], fAs = amps[10];
    const float fBc = ampc[11], fBs = amps[11];
#pragma unroll
    for (int r = 0; r < 16; ++r) {
      float v = base;
      v *= (r & 8) ? f8s : f8c;   // p bit 3 <-> wire 8
      v *= (r & 4) ? f9s : f9c;
      v *= (r & 2) ? fAs : fAc;
      v *= (r & 1) ? fBs : fBc;
      vr[r] = v;
      vi[r] = 0.f;
    }
  }

#define GATE(MASK, ROW, GID)                                             \
  apply_gate<MASK, ROW>(vr, vi,                                          \
      sUre[GID][0], sUim[GID][0], sUre[GID][1], sUim[GID][1],            \
      sUre[GID][2], sUim[GID][2], sUre[GID][3], sUim[GID][3], buf, t)

  // ---- layer 0: L = I, mask = row = e_q, q = 11-w ----
  GATE(0x800, 0x800, 0);    // w=0  (wave bit)  LDS
  GATE(0x400, 0x400, 1);    // w=1  (wave bit)  LDS
  GATE(0x200, 0x200, 2);    // w=2  shfl 32
  GATE(0x100, 0x100, 3);    // w=3  shfl 16
  GATE(0x080, 0x080, 4);    // w=4  shfl 8
  GATE(0x040, 0x040, 5);    // w=5  shfl 4
  GATE(0x020, 0x020, 6);    // w=6  shfl 2
  GATE(0x010, 0x010, 7);    // w=7  shfl 1
  GATE(0x008, 0x008, 8);    // w=8  reg 8
  GATE(0x004, 0x004, 9);    // w=9  reg 4
  GATE(0x002, 0x002, 10);   // w=10 reg 2
  GATE(0x001, 0x001, 11);   // w=11 reg 1

  // ---- layer 1: masks m_q = L1^{-1} e_q, rows = row_q(L1)  (q = 11-w) ----
  GATE(0xC01, 0xFFF, 23);   // w=11 q=0   LDS   -- note: must run LAST; see order below
#undef GATE
  // NOTE: the line above is wrong order -- real sequence below.
  (void)0;

  // --- measurement: sign for wire w = parity(row_{11-w}(L2) & p) ---
  // (unreachable marker removed; real code continues in vqc_kernel2)
  // This path is never taken; see vqc_kernel_real below.
  if (false) { out[0] = 0.f; }
}

// ---------------------------------------------------------------------------
// Real kernel (layer-1 gate order fixed: w = 0..11).
// ---------------------------------------------------------------------------
__global__ __launch_bounds__(256) void vqc_kernel2(
    const float* __restrict__ x,
    const float* __restrict__ Wt,
    const float* __restrict__ tt_bias,
    const float* __restrict__ gang,
    float* __restrict__ out) {
  const int b = blockIdx.x;
  const int t = threadIdx.x;

  __shared__ float buf[8192];
  __shared__ float part[216];
  __shared__ float tt[72];
  __shared__ float sUre[24][4];
  __shared__ float sUim[24][4];
  __shared__ float ampc[N_WIRES], amps[N_WIRES];

  float* xrow = buf;

  ((float4*)xrow)[t] = ((const float4*)(x + (size_t)b * 1024))[t];
  __syncthreads();

  if (t < 216) {
    int o = t % 72, seg = t / 72;
    int j0 = seg * 342;
    int j1 = (seg == 2) ? 1024 : j0 + 342;
    float acc0 = 0.f, acc1 = 0.f;
    int j = j0;
    for (; j + 1 < j1; j += 2) {
      acc0 += xrow[j]     * Wt[j * 72 + o];
      acc1 += xrow[j + 1] * Wt[(j + 1) * 72 + o];
    }
    if (j < j1) acc0 += xrow[j] * Wt[j * 72 + o];
    part[t] = acc0 + acc1;
  }
  __syncthreads();
  if (t < 72) tt[t] = part[t] + part[t + 72] + part[t + 144] + tt_bias[t];
  __syncthreads();

  if (t < 24) {
    int k = t / N_WIRES, w = t - k * N_WIRES;
    float a0 = gang[t * 3 + 0] + tt[k * 36 + w * 3 + 0];
    float a1 = gang[t * 3 + 1] + tt[k * 36 + w * 3 + 1];
    float a2 = gang[t * 3 + 2] + tt[k * 36 + w * 3 + 2];
    float cx = cosf(0.5f * a0), sx = sinf(0.5f * a0);
    float cy = cosf(0.5f * a1), sy = sinf(0.5f * a1);
    float cz = cosf(0.5f * a2), sz = sinf(0.5f * a2);
    float m00r = cy * cx,   m00i = sy * sx;
    float m01r = -sy * cx,  m01i = -cy * sx;
    float m10r = sy * cx,   m10i = -cy * sx;
    float m11r = cy * cx,   m11i = -sy * sx;
    sUre[t][0] = cz * m00r + sz * m00i;  sUim[t][0] = cz * m00i - sz * m00r;
    sUre[t][1] = cz * m01r + sz * m01i;  sUim[t][1] = cz * m01i - sz * m01r;
    sUre[t][2] = cz * m10r - sz * m10i;  sUim[t][2] = cz * m10i + sz * m10r;
    sUre[t][3] = cz * m11r - sz * m11i;  sUim[t][3] = cz * m11i + sz * m11r;
  }
  if (t < N_WIRES) {
    float e = xrow[t] * 0.5f;
    ampc[t] = cosf(e);
    amps[t] = sinf(e);
  }
  __syncthreads();

  float vr[16], vi[16];
  {
    float base = 1.f;
#pragma unroll
    for (int w = 0; w < 8; ++w) {
      int bit = (t >> (7 - w)) & 1;
      base *= bit ? amps[w] : ampc[w];
    }
    const float f8c = ampc[8],  f8s = amps[8];
    const float f9c = ampc[9],  f9s = amps[9];
    const float fAc = ampc[10], fAs = amps[10];
    const float fBc = ampc[11], fBs = amps[11];
#pragma unroll
    for (int r = 0; r < 16; ++r) {
      float v = base;
      v *= (r & 8) ? f8s : f8c;
      v *= (r & 4) ? f9s : f9c;
      v *= (r & 2) ? fAs : fAc;
      v *= (r & 1) ? fBs : fBc;
      vr[r] = v;
      vi[r] = 0.f;
    }
  }

#define GATE(MASK, ROW, GID)                                             \
  apply_gate<MASK, ROW>(vr, vi,                                          \
      sUre[GID][0], sUim[GID][0], sUre[GID][1], sUim[GID][1],            \
      sUre[GID][2], sUim[GID][2], sUre[GID][3], sUim[GID][3], buf, t)

  // ---- layer 0 (L = I): mask = row = 1<<(11-w) ----
  GATE(0x800, 0x800, 0);
  GATE(0x400, 0x400, 1);
  GATE(0x200, 0x200, 2);
  GATE(0x100, 0x100, 3);
  GATE(0x080, 0x080, 4);
  GATE(0x040, 0x040, 5);
  GATE(0x020, 0x020, 6);
  GATE(0x010, 0x010, 7);
  GATE(0x008, 0x008, 8);
  GATE(0x004, 0x004, 9);
  GATE(0x002, 0x002, 10);
  GATE(0x001, 0x001, 11);

  // ---- layer 1 (after CNOT ring; masks = L1^{-1} e_q, rows = row_q(L1)) ----
  GATE(0xC00, 0x7FF, 12);   // w=0  q=11  LDS
  GATE(0x600, 0xC00, 13);   // w=1  q=10  LDS
  GATE(0x300, 0xE00, 14);   // w=2  q=9   shfl 0x30
  GATE(0x180, 0xF00, 15);   // w=3  q=8   shfl 0x18
  GATE(0x0C0, 0xF80, 16);   // w=4  q=7   shfl 0x0C
  GATE(0x060, 0xFC0, 17);   // w=5  q=6   shfl 0x06
  GATE(0x030, 0xFE0, 18);   // w=6  q=5   shfl 0x03
  GATE(0x018, 0xFF0, 19);   // w=7  q=4   shfl 0x01 + reg 8
  GATE(0x00C, 0xFF8, 20);   // w=8  q=3   reg 0xC
  GATE(0x006, 0xFFC, 21);   // w=9  q=2   reg 6
  GATE(0x003, 0xFFE, 22);   // w=10 q=1   reg 3
  GATE(0xC01, 0xFFF, 23);   // w=11 q=0   LDS + reg 1
#undef GATE

  // ---- measurement: sign for out-wire w = parity(row_{11-w}(L2) & p) ----
  constexpr int MROWS[12] = {0xD55, 0xBFF, 0x5FF, 0xAFF, 0x57F, 0xABF,
                             0x55F, 0xAAF, 0x557, 0xAAB, 0x555, 0xAAA};
  float acc[12];
#pragma unroll
  for (int w = 0; w < 12; ++w) acc[w] = 0.f;
#pragma unroll
  for (int r = 0; r < 16; ++r) {
    const float pr = vr[r] * vr[r] + vi[r] * vi[r];
#pragma unroll
    for (int w = 0; w < 12; ++w) {
      if (parity12(MROWS[w] & r)) acc[w] -= pr; else acc[w] += pr;
    }
  }
#pragma unroll
  for (int w = 0; w < 12; ++w) {
    float v = (__popc(MROWS[w] & (t << 4)) & 1) ? -acc[w] : acc[w];
#pragma unroll
    for (int off = 32; off > 0; off >>= 1) v += __shfl_down(v, off, 64);
    if ((t & 63) == 0) part[(t >> 6) * 12 + w] = v;
  }
  __syncthreads();
  if (t < 12) {
    out[(size_t)b * 12 + t] =
        part[t] + part[12 + t] + part[24 + t] + part[36 + t];
  }
}

// ---------------------------------------------------------------------------
extern "C" void kernel_launch(void* const* d_in, const int* in_sizes, int n_in,
                              void* d_out, int out_size, void* d_ws, size_t ws_size,
                              hipStream_t stream) {
  const float* x       = (const float*)d_in[0];
  const float* core0   = (const float*)d_in[1];
  const float* core1   = (const float*)d_in[2];
  const float* tt_bias = (const float*)d_in[3];
  const float* gang    = (const float*)d_in[4];
  float* out = (float*)d_out;
  float* Wt  = (float*)d_ws;           // 73728 floats = 288 KiB scratch

  const int bsz = in_sizes[0] / 1024;  // 2048

  build_w_kernel<<<288, 256, 0, stream>>>(core0, core1, Wt);
  vqc_kernel2<<<bsz, 256, 0, stream>>>(x, Wt, tt_bias, gang, out);
}

// Round 3
// 113.108 us; speedup vs baseline: 1.7579x; 1.1404x over previous
//
#include <hip/hip_runtime.h>
#include <math.h>

#define N_WIRES 12

__host__ __device__ constexpr int parity12(int x) {
  x ^= x >> 8; x ^= x >> 4; x ^= x >> 2; x ^= x >> 1;
  return x & 1;
}

// ---------------------------------------------------------------------------
// Kernel 1: fold the two TT cores into W, row-major by output:
//   Wo[o][k], o = p*9+r (0..71), k = i*32+j (0..1023)
// ---------------------------------------------------------------------------
__global__ __launch_bounds__(256) void build_w_kernel(
    const float* __restrict__ core0,   // (1,32,8,16)
    const float* __restrict__ core1,   // (16,32,9,1)
    float* __restrict__ Wo) {          // (72,1024)
  int idx = blockIdx.x * 256 + threadIdx.x;   // 0..73727
  int o = idx >> 10;          // 0..71
  int k = idx & 1023;
  int i = k >> 5, j = k & 31;
  int p = o / 9, r = o - p * 9;
  float acc = 0.f;
#pragma unroll
  for (int q = 0; q < 16; ++q) {
    acc += core0[(i * 8 + p) * 16 + q] * core1[(q * 32 + j) * 9 + r];
  }
  Wo[idx] = acc;
}

// ---------------------------------------------------------------------------
// Kernel 2: tt_out[b][o] = sum_j x[b][j] * Wo[o][j] + bias[o]
//   grid 512 blocks, 4 rows per block, x tile staged in LDS.
// ---------------------------------------------------------------------------
__global__ __launch_bounds__(256) void tt_gemm_kernel(
    const float* __restrict__ x,       // (2048,1024)
    const float* __restrict__ Wo,      // (72,1024)
    const float* __restrict__ bias,    // (72,)
    float* __restrict__ ttout) {       // (2048,72)
  __shared__ __align__(16) float xt[4 * 1024];
  const int t = threadIdx.x;
  const int row0 = blockIdx.x * 4;

  const float4* xg = (const float4*)(x + (size_t)row0 * 1024);
#pragma unroll
  for (int i = 0; i < 4; ++i) ((float4*)xt)[i * 256 + t] = xg[i * 256 + t];
  __syncthreads();

#pragma unroll
  for (int p = 0; p < 2; ++p) {
    int oi = p * 256 + t;
    if (oi < 288) {
      int row = oi / 72, o = oi - row * 72;
      const float4* wr = (const float4*)(Wo + o * 1024);
      const float4* xr = (const float4*)(xt + row * 1024);
      float a0 = 0.f, a1 = 0.f, a2 = 0.f, a3 = 0.f;
#pragma unroll 4
      for (int j = 0; j < 256; ++j) {
        float4 wv = wr[j];
        float4 xv = xr[j];
        a0 += wv.x * xv.x; a1 += wv.y * xv.y;
        a2 += wv.z * xv.z; a3 += wv.w * xv.w;
      }
      ttout[(size_t)(row0 + row) * 72 + o] = a0 + a1 + a2 + a3 + bias[o];
    }
  }
}

// ---------------------------------------------------------------------------
// Single-qubit gate on register-resident state in the B-transformed basis.
//   Storage index s = (t<<4) | r.  Pairing: s <-> s ^ MASK.
//   Branch bit = parity(ROW & s).
//   MASK bits 0-3: register xor; 4-9: lane xor (shfl); 10-11: wave (LDS).
// ---------------------------------------------------------------------------
template <int MASK, int ROW>
__device__ __forceinline__ void apply_gate(
    float vr[16], float vi[16],
    float u00r, float u00i, float u01r, float u01i,
    float u10r, float u10i, float u11r, float u11i,
    float* __restrict__ buf, int t) {
  constexpr int RM = MASK & 15;
  constexpr int TM = (MASK >> 4) & 0xFF;
  constexpr int LM = TM & 63;
  constexpr bool LDSX = (TM & 0xC0) != 0;

  const int tpar = __popc(ROW & (t << 4)) & 1;
  const float aor = tpar ? u11r : u00r, aoi = tpar ? u11i : u00i;
  const float apr = tpar ? u10r : u01r, api = tpar ? u10i : u01i;
  const float qor = tpar ? u00r : u11r, qoi = tpar ? u00i : u11i;
  const float qpr = tpar ? u01r : u10r, qpi = tpar ? u01i : u10i;

  auto upd = [&](int r, float ar, float ai, float br, float bi,
                 float& xr, float& xi) {
    const bool b1 = parity12(ROW & r);           // folds (r unrolled-const)
    const float cor = b1 ? qor : aor, coi = b1 ? qoi : aoi;
    const float cpr = b1 ? qpr : apr, cpi = b1 ? qpi : api;
    const float nr = cor * ar - coi * ai + cpr * br - cpi * bi;
    const float ni = cor * ai + coi * ar + cpr * bi + cpi * br;
    xr = nr; xi = ni;
  };

  if constexpr (LDSX) {
    const int tp = t ^ TM;
    if constexpr ((RM & 8) == 0) {
      // partners stay within each register half: exchange 8 regs at a time
      __syncthreads();
#pragma unroll
      for (int r = 8; r < 16; ++r) {
        buf[(r & 7) * 256 + t] = vr[r];
        buf[2048 + (r & 7) * 256 + t] = vi[r];
      }
      __syncthreads();
#pragma unroll
      for (int r = 8; r < 16; ++r) {
        const int r2 = r ^ RM;                   // stays in [8,16)
        const float br = buf[(r2 & 7) * 256 + tp];
        const float bi = buf[2048 + (r2 & 7) * 256 + tp];
        upd(r, vr[r], vi[r], br, bi, vr[r], vi[r]);
      }
      __syncthreads();
#pragma unroll
      for (int r = 0; r < 8; ++r) {
        buf[r * 256 + t] = vr[r];
        buf[2048 + r * 256 + t] = vi[r];
      }
      __syncthreads();
#pragma unroll
      for (int r = 0; r < 8; ++r) {
        const int r2 = r ^ RM;                   // stays in [0,8)
        const float br = buf[r2 * 256 + tp];
        const float bi = buf[2048 + r2 * 256 + tp];
        upd(r, vr[r], vi[r], br, bi, vr[r], vi[r]);
      }
    } else {
      // RM crosses the register halves (e.g. RM=0xF)
      __syncthreads();
#pragma unroll
      for (int r = 8; r < 16; ++r) {
        buf[(r & 7) * 256 + t] = vr[r];
        buf[2048 + (r & 7) * 256 + t] = vi[r];
      }
      __syncthreads();
      float tr[8], ti[8];
#pragma unroll
      for (int r = 0; r < 8; ++r) {
        const int r2 = r ^ RM;                   // in [8,16)
        const float br = buf[(r2 & 7) * 256 + tp];
        const float bi = buf[2048 + (r2 & 7) * 256 + tp];
        upd(r, vr[r], vi[r], br, bi, tr[r], ti[r]);
      }
      __syncthreads();
#pragma unroll
      for (int r = 0; r < 8; ++r) {
        buf[r * 256 + t] = vr[r];                // old values, still intact
        buf[2048 + r * 256 + t] = vi[r];
      }
      __syncthreads();
#pragma unroll
      for (int r = 8; r < 16; ++r) {
        const int r2 = r ^ RM;                   // in [0,8)
        const float br = buf[r2 * 256 + tp];
        const float bi = buf[2048 + r2 * 256 + tp];
        upd(r, vr[r], vi[r], br, bi, vr[r], vi[r]);
      }
#pragma unroll
      for (int r = 0; r < 8; ++r) { vr[r] = tr[r]; vi[r] = ti[r]; }
    }
  } else if constexpr (LM != 0) {
    static_assert(!(LM != 0) || RM == 0, "shfl gates have no reg component");
#pragma unroll
    for (int r = 0; r < 16; ++r) {
      const float br = __shfl_xor(vr[r], LM, 64);
      const float bi = __shfl_xor(vi[r], LM, 64);
      upd(r, vr[r], vi[r], br, bi, vr[r], vi[r]);
    }
  } else {
#pragma unroll
    for (int r = 0; r < 16; ++r) {
      if (r < (r ^ RM)) {
        const int r2 = r ^ RM;
        const float ar = vr[r], ai = vi[r];
        const float br = vr[r2], bi = vi[r2];
        upd(r, ar, ai, br, bi, vr[r], vi[r]);
        upd(r2, br, bi, ar, ai, vr[r2], vi[r2]);
      }
    }
  }
}

// ---------------------------------------------------------------------------
// Kernel 3: statevector sim, one block per batch row.
//   Layer-0 folded into the product-state init (per-wire f_w = U0_w (c,s)^T).
//   Storage basis B maps layer-1 masks to single bits; bit of wire w at
//   storage s: w0:s11, w1:s10^s9(as t-bits 6^5)... (see init), derived from
//   B^-1 rows {0x001,0x003,0x006,...,0x300,0x600,0x800}.
// ---------------------------------------------------------------------------
__global__ __launch_bounds__(256, 5) void vqc_kernel3(
    const float* __restrict__ x,        // (2048,1024) -- only first 12 cols used
    const float* __restrict__ ttout,    // (2048,72)
    const float* __restrict__ gang,     // (2,12,3)
    float* __restrict__ out) {          // (2048,12)
  const int b = blockIdx.x;
  const int t = threadIdx.x;

  __shared__ __align__(16) float buf[4096];    // 16 KiB exchange / reduce
  __shared__ float sUre[12][4], sUim[12][4];   // layer-1 unitaries
  __shared__ float sFre[12][2], sFim[12][2];   // layer-0 product vectors

  const float* ttb = ttout + (size_t)b * 72;

  if (t < 24) {
    const int w = (t < 12) ? t : t - 12;
    const int k = (t < 12) ? 1 : 0;
    const int gbase = (k * 12 + w) * 3;
    const int tbase = k * 36 + w * 3;
    float a0 = gang[gbase + 0] + ttb[tbase + 0];
    float a1 = gang[gbase + 1] + ttb[tbase + 1];
    float a2 = gang[gbase + 2] + ttb[tbase + 2];
    float cx = cosf(0.5f * a0), sx = sinf(0.5f * a0);
    float cy = cosf(0.5f * a1), sy = sinf(0.5f * a1);
    float cz = cosf(0.5f * a2), sz = sinf(0.5f * a2);
    // M = Ry @ Rx
    float m00r = cy * cx,   m00i = sy * sx;
    float m01r = -sy * cx,  m01i = -cy * sx;
    float m10r = sy * cx,   m10i = -cy * sx;
    float m11r = cy * cx,   m11i = -sy * sx;
    // U = Rz @ M
    float U00r = cz * m00r + sz * m00i, U00i = cz * m00i - sz * m00r;
    float U01r = cz * m01r + sz * m01i, U01i = cz * m01i - sz * m01r;
    float U10r = cz * m10r - sz * m10i, U10i = cz * m10i + sz * m10r;
    float U11r = cz * m11r - sz * m11i, U11i = cz * m11i + sz * m11r;
    if (t < 12) {
      sUre[w][0] = U00r; sUim[w][0] = U00i;
      sUre[w][1] = U01r; sUim[w][1] = U01i;
      sUre[w][2] = U10r; sUim[w][2] = U10i;
      sUre[w][3] = U11r; sUim[w][3] = U11i;
    } else {
      const float e = x[(size_t)b * 1024 + w] * 0.5f;
      const float c = cosf(e), s = sinf(e);
      sFre[w][0] = U00r * c + U01r * s;  sFim[w][0] = U00i * c + U01i * s;
      sFre[w][1] = U10r * c + U11r * s;  sFim[w][1] = U10i * c + U11i * s;
    }
  }
  __syncthreads();

  // --- product-state init in the B basis ---
  float vr[16], vi[16];
  {
    const int bits[7] = {(t >> 7) & 1,
                         ((t >> 6) ^ (t >> 5)) & 1,
                         ((t >> 5) ^ (t >> 4)) & 1,
                         ((t >> 4) ^ (t >> 3)) & 1,
                         ((t >> 3) ^ (t >> 2)) & 1,
                         ((t >> 2) ^ (t >> 1)) & 1,
                         ((t >> 1) ^ t) & 1};
    float br_ = 1.f, bi_ = 0.f;
#pragma unroll
    for (int w = 0; w < 7; ++w) {
      const float fr = sFre[w][bits[w]], fi = sFim[w][bits[w]];
      const float nr = br_ * fr - bi_ * fi;
      const float ni = br_ * fi + bi_ * fr;
      br_ = nr; bi_ = ni;
    }
    const int t0 = t & 1;
    float b7r[2], b7i[2];
#pragma unroll
    for (int r3 = 0; r3 < 2; ++r3) {
      const float fr = sFre[7][t0 ^ r3], fi = sFim[7][t0 ^ r3];
      b7r[r3] = br_ * fr - bi_ * fi;
      b7i[r3] = br_ * fi + bi_ * fr;
    }
    float hr[8], hi[8];
#pragma unroll
    for (int j = 0; j < 8; ++j) {
      const int r3 = j >> 2, r2 = (j >> 1) & 1, r1 = j & 1;
      const float ar = sFre[8][r3 ^ r2], ai = sFim[8][r3 ^ r2];
      const float cr = sFre[9][r2 ^ r1], ci = sFim[9][r2 ^ r1];
      hr[j] = ar * cr - ai * ci; hi[j] = ar * ci + ai * cr;
    }
    float gr[4], gi[4];
#pragma unroll
    for (int j = 0; j < 4; ++j) {
      const int r1 = j >> 1, r0 = j & 1;
      const float ar = sFre[10][r1 ^ r0], ai = sFim[10][r1 ^ r0];
      const float cr = sFre[11][r0], ci = sFim[11][r0];
      gr[j] = ar * cr - ai * ci; gi[j] = ar * ci + ai * cr;
    }
#pragma unroll
    for (int r = 0; r < 16; ++r) {
      const int r3 = r >> 3, hj = r >> 1, gj = r & 3;
      const float pr = hr[hj] * gr[gj] - hi[hj] * gi[gj];
      const float pi = hr[hj] * gi[gj] + hi[hj] * gr[gj];
      vr[r] = b7r[r3] * pr - b7i[r3] * pi;
      vi[r] = b7r[r3] * pi + b7i[r3] * pr;
    }
  }

#define GATE(MASK, ROW, GID)                                             \
  apply_gate<MASK, ROW>(vr, vi,                                          \
      sUre[GID][0], sUim[GID][0], sUre[GID][1], sUim[GID][1],            \
      sUre[GID][2], sUim[GID][2], sUre[GID][3], sUim[GID][3], buf, t)

  // ---- layer 1 in B basis (masks B*m, rows r*B^-1); layer 0 is in init ----
  GATE(0xC00, 0x400, 0);    // w=0   LDS (wave bits)
  GATE(0x200, 0xE00, 1);    // w=1   shfl 0x20
  GATE(0x100, 0xD00, 2);    // w=2   shfl 0x10
  GATE(0x080, 0xC80, 3);    // w=3   shfl 8
  GATE(0x040, 0xC40, 4);    // w=4   shfl 4
  GATE(0x020, 0xC20, 5);    // w=5   shfl 2
  GATE(0x010, 0xC10, 6);    // w=6   shfl 1
  GATE(0x008, 0xC08, 7);    // w=7   reg 8
  GATE(0x004, 0xC04, 8);    // w=8   reg 4
  GATE(0x002, 0xC02, 9);    // w=9   reg 2
  GATE(0x001, 0xC01, 10);   // w=10  reg 1
  GATE(0xBFF, 0xC00, 11);   // w=11  LDS + lane + reg
#undef GATE

  // ---- measurement: sign(w, s) = parity(MROWS[w] & s) ----
  constexpr int MROWS[12] = {0xFFF, 0xA00, 0x700, 0xB80, 0x7C0, 0xBE0,
                             0x7F0, 0xBF8, 0x7FC, 0xBFE, 0x7FF, 0xBFF};
  float acc[12];
#pragma unroll
  for (int w = 0; w < 12; ++w) acc[w] = 0.f;
#pragma unroll
  for (int r = 0; r < 16; ++r) {
    const float pr = vr[r] * vr[r] + vi[r] * vi[r];
#pragma unroll
    for (int w = 0; w < 12; ++w) {
      if (parity12(MROWS[w] & r)) acc[w] -= pr; else acc[w] += pr;
    }
  }
  __syncthreads();                       // buf reads of gate 11 done
#pragma unroll
  for (int w = 0; w < 12; ++w) {
    float v = (__popc(MROWS[w] & (t << 4)) & 1) ? -acc[w] : acc[w];
#pragma unroll
    for (int off = 32; off > 0; off >>= 1) v += __shfl_down(v, off, 64);
    if ((t & 63) == 0) buf[(t >> 6) * 12 + w] = v;
  }
  __syncthreads();
  if (t < 12) {
    out[(size_t)b * 12 + t] = buf[t] + buf[12 + t] + buf[24 + t] + buf[36 + t];
  }
}

// ---------------------------------------------------------------------------
extern "C" void kernel_launch(void* const* d_in, const int* in_sizes, int n_in,
                              void* d_out, int out_size, void* d_ws, size_t ws_size,
                              hipStream_t stream) {
  const float* x       = (const float*)d_in[0];
  const float* core0   = (const float*)d_in[1];
  const float* core1   = (const float*)d_in[2];
  const float* tt_bias = (const float*)d_in[3];
  const float* gang    = (const float*)d_in[4];
  float* out = (float*)d_out;
  float* Wo     = (float*)d_ws;                 // 72*1024 floats = 288 KiB
  float* ttout  = (float*)d_ws + 73728;         // 2048*72 floats = 576 KiB

  const int bsz = in_sizes[0] / 1024;  // 2048

  build_w_kernel<<<288, 256, 0, stream>>>(core0, core1, Wo);
  tt_gemm_kernel<<<bsz / 4, 256, 0, stream>>>(x, Wo, tt_bias, ttout);
  vqc_kernel3<<<bsz, 256, 0, stream>>>(x, ttout, gang, out);
}

// Round 4
// 58.886 us; speedup vs baseline: 3.3766x; 1.9208x over previous
//
#include <hip/hip_runtime.h>
#include <math.h>

#define N_WIRES 12

__host__ __device__ constexpr int parity12(int x) {
  x ^= x >> 8; x ^= x >> 4; x ^= x >> 2; x ^= x >> 1;
  return x & 1;
}

// ---------------------------------------------------------------------------
// Kernel 1: fold the two TT cores into W, padded layout:
//   Wt[k][og*12 + j] = W[k][o],  o = og*9 + j  (j<9; slots 9..11 unused)
//   k = i*32+jj (0..1023), o = p*9+r (0..71)
// ---------------------------------------------------------------------------
__global__ __launch_bounds__(256) void build_w_kernel(
    const float* __restrict__ core0,   // (1,32,8,16)
    const float* __restrict__ core1,   // (16,32,9,1)
    float* __restrict__ Wt) {          // (1024,96) padded
  int idx = blockIdx.x * 256 + threadIdx.x;   // 0..73727
  int k = idx / 72;
  int o = idx - k * 72;
  int i = k >> 5, jj = k & 31;
  int p = o / 9, r = o - p * 9;
  float acc = 0.f;
#pragma unroll
  for (int q = 0; q < 16; ++q) {
    acc += core0[(i * 8 + p) * 16 + q] * core1[(q * 32 + jj) * 9 + r];
  }
  int og = o / 9, j = o - og * 9;
  Wt[k * 96 + og * 12 + j] = acc;
}

// ---------------------------------------------------------------------------
// Kernel 2: tt_out[b][o] = sum_k x[b][k] * W[k][o] + bias[o]
//   512 threads, 8 rows/block, K in 8 LDS-staged slices of 128.
//   Thread (kk,rp,og): kk=t>>5 (k-stride-16 lanes), rp=(t>>3)&3 (row pair),
//   og=t&7 (9 outputs og*9..og*9+8). All global traffic coalesced; compute
//   reads are LDS with <=2-way bank aliasing.
// ---------------------------------------------------------------------------
__global__ __launch_bounds__(512) void tt_gemm2(
    const float* __restrict__ x,       // (2048,1024)
    const float* __restrict__ Wt,      // (1024,96) padded
    const float* __restrict__ bias,    // (72,)
    float* __restrict__ ttout) {       // (2048,72)
  __shared__ __align__(16) float ws[128 * 96];    // 49.2 KB W slice
  __shared__ __align__(16) float xs[8 * 132];     // 4.2 KB  x slice
  __shared__ float part[16 * 8 * 73];             // 37.4 KB kk-partials
  const int t = threadIdx.x;
  const int row0 = blockIdx.x * 8;
  const int kk = t >> 5;           // 0..15
  const int rp = (t >> 3) & 3;     // 0..3
  const int og = t & 7;            // 0..7
  const int r0 = rp * 2;

  float a0[9], a1[9];
#pragma unroll
  for (int j = 0; j < 9; ++j) { a0[j] = 0.f; a1[j] = 0.f; }

  for (int s = 0; s < 8; ++s) {
    __syncthreads();                       // previous slice's reads done
    // --- stage W slice: flat copy of 128*96 floats = 3072 float4 ---
    const float4* Wg = (const float4*)(Wt + s * 128 * 96);
#pragma unroll
    for (int i = 0; i < 6; ++i) {
      const int idx = i * 512 + t;         // 0..3071
      ((float4*)ws)[idx] = Wg[idx];
    }
    // --- stage x slice: 8 rows x 128 k = 256 float4 ---
    if (t < 256) {
      const int rr = t >> 5, j4 = t & 31;
      *(float4*)&xs[rr * 132 + j4 * 4] =
          *(const float4*)(x + (size_t)(row0 + rr) * 1024 + s * 128 + j4 * 4);
    }
    __syncthreads();
    // --- compute: 8 k-iters, 2 rows x 9 outputs each ---
#pragma unroll
    for (int i = 0; i < 8; ++i) {
      const int k = kk + i * 16;
      const float4 wA = *(const float4*)&ws[k * 96 + og * 12];
      const float4 wB = *(const float4*)&ws[k * 96 + og * 12 + 4];
      const float w8 = ws[k * 96 + og * 12 + 8];
      const float x0v = xs[r0 * 132 + k];
      const float x1v = xs[r0 * 132 + 132 + k];
      a0[0] += x0v * wA.x; a0[1] += x0v * wA.y;
      a0[2] += x0v * wA.z; a0[3] += x0v * wA.w;
      a0[4] += x0v * wB.x; a0[5] += x0v * wB.y;
      a0[6] += x0v * wB.z; a0[7] += x0v * wB.w;
      a0[8] += x0v * w8;
      a1[0] += x1v * wA.x; a1[1] += x1v * wA.y;
      a1[2] += x1v * wA.z; a1[3] += x1v * wA.w;
      a1[4] += x1v * wB.x; a1[5] += x1v * wB.y;
      a1[6] += x1v * wB.z; a1[7] += x1v * wB.w;
      a1[8] += x1v * w8;
    }
  }

  // --- write kk-partials (disjoint slots per thread) ---
#pragma unroll
  for (int j = 0; j < 9; ++j) {
    part[(kk * 8 + r0) * 73 + og * 9 + j] = a0[j];
    part[(kk * 8 + r0 + 1) * 73 + og * 9 + j] = a1[j];
  }
  __syncthreads();

  // --- reduce over kk, add bias, write ---
  for (int i = t; i < 576; i += 512) {
    const int r = i / 72, o = i - r * 72;
    float ssum = bias[o];
#pragma unroll
    for (int kq = 0; kq < 16; ++kq) ssum += part[(kq * 8 + r) * 73 + o];
    ttout[(size_t)(row0 + r) * 72 + o] = ssum;
  }
}

// ---------------------------------------------------------------------------
// Single-qubit gate on register-resident state in the B-transformed basis.
//   Storage index s = (t<<4) | r.  Pairing: s <-> s ^ MASK.
//   Branch bit = parity(ROW & s).
//   MASK bits 0-3: register xor; 4-9: lane xor (shfl); 10-11: wave (LDS).
// ---------------------------------------------------------------------------
template <int MASK, int ROW>
__device__ __forceinline__ void apply_gate(
    float vr[16], float vi[16],
    float u00r, float u00i, float u01r, float u01i,
    float u10r, float u10i, float u11r, float u11i,
    float* __restrict__ buf, int t) {
  constexpr int RM = MASK & 15;
  constexpr int TM = (MASK >> 4) & 0xFF;
  constexpr int LM = TM & 63;
  constexpr bool LDSX = (TM & 0xC0) != 0;

  const int tpar = __popc(ROW & (t << 4)) & 1;
  const float aor = tpar ? u11r : u00r, aoi = tpar ? u11i : u00i;
  const float apr = tpar ? u10r : u01r, api = tpar ? u10i : u01i;
  const float qor = tpar ? u00r : u11r, qoi = tpar ? u00i : u11i;
  const float qpr = tpar ? u01r : u10r, qpi = tpar ? u01i : u10i;

  auto upd = [&](int r, float ar, float ai, float br, float bi,
                 float& xr, float& xi) {
    const bool b1 = parity12(ROW & r);
    const float cor = b1 ? qor : aor, coi = b1 ? qoi : aoi;
    const float cpr = b1 ? qpr : apr, cpi = b1 ? qpi : api;
    const float nr = cor * ar - coi * ai + cpr * br - cpi * bi;
    const float ni = cor * ai + coi * ar + cpr * bi + cpi * br;
    xr = nr; xi = ni;
  };

  if constexpr (LDSX) {
    const int tp = t ^ TM;
    if constexpr ((RM & 8) == 0) {
      __syncthreads();
#pragma unroll
      for (int r = 8; r < 16; ++r) {
        buf[(r & 7) * 256 + t] = vr[r];
        buf[2048 + (r & 7) * 256 + t] = vi[r];
      }
      __syncthreads();
#pragma unroll
      for (int r = 8; r < 16; ++r) {
        const int r2 = r ^ RM;
        const float br = buf[(r2 & 7) * 256 + tp];
        const float bi = buf[2048 + (r2 & 7) * 256 + tp];
        upd(r, vr[r], vi[r], br, bi, vr[r], vi[r]);
      }
      __syncthreads();
#pragma unroll
      for (int r = 0; r < 8; ++r) {
        buf[r * 256 + t] = vr[r];
        buf[2048 + r * 256 + t] = vi[r];
      }
      __syncthreads();
#pragma unroll
      for (int r = 0; r < 8; ++r) {
        const int r2 = r ^ RM;
        const float br = buf[r2 * 256 + tp];
        const float bi = buf[2048 + r2 * 256 + tp];
        upd(r, vr[r], vi[r], br, bi, vr[r], vi[r]);
      }
    } else {
      __syncthreads();
#pragma unroll
      for (int r = 8; r < 16; ++r) {
        buf[(r & 7) * 256 + t] = vr[r];
        buf[2048 + (r & 7) * 256 + t] = vi[r];
      }
      __syncthreads();
      float tr[8], ti[8];
#pragma unroll
      for (int r = 0; r < 8; ++r) {
        const int r2 = r ^ RM;
        const float br = buf[(r2 & 7) * 256 + tp];
        const float bi = buf[2048 + (r2 & 7) * 256 + tp];
        upd(r, vr[r], vi[r], br, bi, tr[r], ti[r]);
      }
      __syncthreads();
#pragma unroll
      for (int r = 0; r < 8; ++r) {
        buf[r * 256 + t] = vr[r];
        buf[2048 + r * 256 + t] = vi[r];
      }
      __syncthreads();
#pragma unroll
      for (int r = 8; r < 16; ++r) {
        const int r2 = r ^ RM;
        const float br = buf[r2 * 256 + tp];
        const float bi = buf[2048 + r2 * 256 + tp];
        upd(r, vr[r], vi[r], br, bi, vr[r], vi[r]);
      }
#pragma unroll
      for (int r = 0; r < 8; ++r) { vr[r] = tr[r]; vi[r] = ti[r]; }
    }
  } else if constexpr (LM != 0) {
    static_assert(!(LM != 0) || RM == 0, "shfl gates have no reg component");
#pragma unroll
    for (int r = 0; r < 16; ++r) {
      const float br = __shfl_xor(vr[r], LM, 64);
      const float bi = __shfl_xor(vi[r], LM, 64);
      upd(r, vr[r], vi[r], br, bi, vr[r], vi[r]);
    }
  } else {
#pragma unroll
    for (int r = 0; r < 16; ++r) {
      if (r < (r ^ RM)) {
        const int r2 = r ^ RM;
        const float ar = vr[r], ai = vi[r];
        const float br = vr[r2], bi = vi[r2];
        upd(r, ar, ai, br, bi, vr[r], vi[r]);
        upd(r2, br, bi, ar, ai, vr[r2], vi[r2]);
      }
    }
  }
}

// ---------------------------------------------------------------------------
// Kernel 3: statevector sim, one block per batch row (unchanged from R2).
// ---------------------------------------------------------------------------
__global__ __launch_bounds__(256, 5) void vqc_kernel3(
    const float* __restrict__ x,        // (2048,1024) -- only first 12 cols used
    const float* __restrict__ ttout,    // (2048,72)
    const float* __restrict__ gang,     // (2,12,3)
    float* __restrict__ out) {          // (2048,12)
  const int b = blockIdx.x;
  const int t = threadIdx.x;

  __shared__ __align__(16) float buf[4096];
  __shared__ float sUre[12][4], sUim[12][4];
  __shared__ float sFre[12][2], sFim[12][2];

  const float* ttb = ttout + (size_t)b * 72;

  if (t < 24) {
    const int w = (t < 12) ? t : t - 12;
    const int k = (t < 12) ? 1 : 0;
    const int gbase = (k * 12 + w) * 3;
    const int tbase = k * 36 + w * 3;
    float a0 = gang[gbase + 0] + ttb[tbase + 0];
    float a1 = gang[gbase + 1] + ttb[tbase + 1];
    float a2 = gang[gbase + 2] + ttb[tbase + 2];
    float cx = cosf(0.5f * a0), sx = sinf(0.5f * a0);
    float cy = cosf(0.5f * a1), sy = sinf(0.5f * a1);
    float cz = cosf(0.5f * a2), sz = sinf(0.5f * a2);
    float m00r = cy * cx,   m00i = sy * sx;
    float m01r = -sy * cx,  m01i = -cy * sx;
    float m10r = sy * cx,   m10i = -cy * sx;
    float m11r = cy * cx,   m11i = -sy * sx;
    float U00r = cz * m00r + sz * m00i, U00i = cz * m00i - sz * m00r;
    float U01r = cz * m01r + sz * m01i, U01i = cz * m01i - sz * m01r;
    float U10r = cz * m10r - sz * m10i, U10i = cz * m10i + sz * m10r;
    float U11r = cz * m11r - sz * m11i, U11i = cz * m11i + sz * m11r;
    if (t < 12) {
      sUre[w][0] = U00r; sUim[w][0] = U00i;
      sUre[w][1] = U01r; sUim[w][1] = U01i;
      sUre[w][2] = U10r; sUim[w][2] = U10i;
      sUre[w][3] = U11r; sUim[w][3] = U11i;
    } else {
      const float e = x[(size_t)b * 1024 + w] * 0.5f;
      const float c = cosf(e), s = sinf(e);
      sFre[w][0] = U00r * c + U01r * s;  sFim[w][0] = U00i * c + U01i * s;
      sFre[w][1] = U10r * c + U11r * s;  sFim[w][1] = U10i * c + U11i * s;
    }
  }
  __syncthreads();

  float vr[16], vi[16];
  {
    const int bits[7] = {(t >> 7) & 1,
                         ((t >> 6) ^ (t >> 5)) & 1,
                         ((t >> 5) ^ (t >> 4)) & 1,
                         ((t >> 4) ^ (t >> 3)) & 1,
                         ((t >> 3) ^ (t >> 2)) & 1,
                         ((t >> 2) ^ (t >> 1)) & 1,
                         ((t >> 1) ^ t) & 1};
    float br_ = 1.f, bi_ = 0.f;
#pragma unroll
    for (int w = 0; w < 7; ++w) {
      const float fr = sFre[w][bits[w]], fi = sFim[w][bits[w]];
      const float nr = br_ * fr - bi_ * fi;
      const float ni = br_ * fi + bi_ * fr;
      br_ = nr; bi_ = ni;
    }
    const int t0 = t & 1;
    float b7r[2], b7i[2];
#pragma unroll
    for (int r3 = 0; r3 < 2; ++r3) {
      const float fr = sFre[7][t0 ^ r3], fi = sFim[7][t0 ^ r3];
      b7r[r3] = br_ * fr - bi_ * fi;
      b7i[r3] = br_ * fi + bi_ * fr;
    }
    float hr[8], hi[8];
#pragma unroll
    for (int j = 0; j < 8; ++j) {
      const int r3 = j >> 2, r2 = (j >> 1) & 1, r1 = j & 1;
      const float ar = sFre[8][r3 ^ r2], ai = sFim[8][r3 ^ r2];
      const float cr = sFre[9][r2 ^ r1], ci = sFim[9][r2 ^ r1];
      hr[j] = ar * cr - ai * ci; hi[j] = ar * ci + ai * cr;
    }
    float gr[4], gi[4];
#pragma unroll
    for (int j = 0; j < 4; ++j) {
      const int r1 = j >> 1, r0 = j & 1;
      const float ar = sFre[10][r1 ^ r0], ai = sFim[10][r1 ^ r0];
      const float cr = sFre[11][r0], ci = sFim[11][r0];
      gr[j] = ar * cr - ai * ci; gi[j] = ar * ci + ai * cr;
    }
#pragma unroll
    for (int r = 0; r < 16; ++r) {
      const int r3 = r >> 3, hj = r >> 1, gj = r & 3;
      const float pr = hr[hj] * gr[gj] - hi[hj] * gi[gj];
      const float pi = hr[hj] * gi[gj] + hi[hj] * gr[gj];
      vr[r] = b7r[r3] * pr - b7i[r3] * pi;
      vi[r] = b7r[r3] * pi + b7i[r3] * pr;
    }
  }

#define GATE(MASK, ROW, GID)                                             \
  apply_gate<MASK, ROW>(vr, vi,                                          \
      sUre[GID][0], sUim[GID][0], sUre[GID][1], sUim[GID][1],            \
      sUre[GID][2], sUim[GID][2], sUre[GID][3], sUim[GID][3], buf, t)

  GATE(0xC00, 0x400, 0);    // w=0   LDS (wave bits)
  GATE(0x200, 0xE00, 1);    // w=1   shfl 0x20
  GATE(0x100, 0xD00, 2);    // w=2   shfl 0x10
  GATE(0x080, 0xC80, 3);    // w=3   shfl 8
  GATE(0x040, 0xC40, 4);    // w=4   shfl 4
  GATE(0x020, 0xC20, 5);    // w=5   shfl 2
  GATE(0x010, 0xC10, 6);    // w=6   shfl 1
  GATE(0x008, 0xC08, 7);    // w=7   reg 8
  GATE(0x004, 0xC04, 8);    // w=8   reg 4
  GATE(0x002, 0xC02, 9);    // w=9   reg 2
  GATE(0x001, 0xC01, 10);   // w=10  reg 1
  GATE(0xBFF, 0xC00, 11);   // w=11  LDS + lane + reg
#undef GATE

  constexpr int MROWS[12] = {0xFFF, 0xA00, 0x700, 0xB80, 0x7C0, 0xBE0,
                             0x7F0, 0xBF8, 0x7FC, 0xBFE, 0x7FF, 0xBFF};
  float acc[12];
#pragma unroll
  for (int w = 0; w < 12; ++w) acc[w] = 0.f;
#pragma unroll
  for (int r = 0; r < 16; ++r) {
    const float pr = vr[r] * vr[r] + vi[r] * vi[r];
#pragma unroll
    for (int w = 0; w < 12; ++w) {
      if (parity12(MROWS[w] & r)) acc[w] -= pr; else acc[w] += pr;
    }
  }
  __syncthreads();
#pragma unroll
  for (int w = 0; w < 12; ++w) {
    float v = (__popc(MROWS[w] & (t << 4)) & 1) ? -acc[w] : acc[w];
#pragma unroll
    for (int off = 32; off > 0; off >>= 1) v += __shfl_down(v, off, 64);
    if ((t & 63) == 0) buf[(t >> 6) * 12 + w] = v;
  }
  __syncthreads();
  if (t < 12) {
    out[(size_t)b * 12 + t] = buf[t] + buf[12 + t] + buf[24 + t] + buf[36 + t];
  }
}

// ---------------------------------------------------------------------------
extern "C" void kernel_launch(void* const* d_in, const int* in_sizes, int n_in,
                              void* d_out, int out_size, void* d_ws, size_t ws_size,
                              hipStream_t stream) {
  const float* x       = (const float*)d_in[0];
  const float* core0   = (const float*)d_in[1];
  const float* core1   = (const float*)d_in[2];
  const float* tt_bias = (const float*)d_in[3];
  const float* gang    = (const float*)d_in[4];
  float* out = (float*)d_out;
  float* Wt     = (float*)d_ws;                 // 1024*96 floats = 384 KiB
  float* ttout  = (float*)d_ws + 98304;         // 2048*72 floats = 576 KiB

  const int bsz = in_sizes[0] / 1024;  // 2048

  build_w_kernel<<<288, 256, 0, stream>>>(core0, core1, Wt);
  tt_gemm2<<<bsz / 8, 512, 0, stream>>>(x, Wt, tt_bias, ttout);
  vqc_kernel3<<<bsz, 256, 0, stream>>>(x, ttout, gang, out);
}

// Round 5
// 58.787 us; speedup vs baseline: 3.3823x; 1.0017x over previous
//
#include <hip/hip_runtime.h>
#include <math.h>

#define N_WIRES 12

__host__ __device__ constexpr int parity12(int x) {
  x ^= x >> 8; x ^= x >> 4; x ^= x >> 2; x ^= x >> 1;
  return x & 1;
}

typedef float2 f2;
__device__ __forceinline__ f2 mk2(float a, float b) { f2 r; r.x = a; r.y = b; return r; }
__device__ __forceinline__ f2 pkmul(f2 a, f2 b) {
  f2 d; asm("v_pk_mul_f32 %0, %1, %2" : "=v"(d) : "v"(a), "v"(b)); return d;
}
__device__ __forceinline__ f2 pkfma(f2 a, f2 b, f2 c) {
  f2 d; asm("v_pk_fma_f32 %0, %1, %2, %3" : "=v"(d) : "v"(a), "v"(b), "v"(c)); return d;
}
__device__ __forceinline__ f2 shfl_xor2(f2 v, int m) {
  f2 r; r.x = __shfl_xor(v.x, m, 64); r.y = __shfl_xor(v.y, m, 64); return r;
}
__device__ __forceinline__ f2 swap2(f2 v) { return mk2(v.y, v.x); }

// ---------------------------------------------------------------------------
// Kernel 1: fold the two TT cores into W, padded layout (unchanged from R3).
// ---------------------------------------------------------------------------
__global__ __launch_bounds__(256) void build_w_kernel(
    const float* __restrict__ core0,   // (1,32,8,16)
    const float* __restrict__ core1,   // (16,32,9,1)
    float* __restrict__ Wt) {          // (1024,96) padded
  int idx = blockIdx.x * 256 + threadIdx.x;   // 0..73727
  int k = idx / 72;
  int o = idx - k * 72;
  int i = k >> 5, jj = k & 31;
  int p = o / 9, r = o - p * 9;
  float acc = 0.f;
#pragma unroll
  for (int q = 0; q < 16; ++q) {
    acc += core0[(i * 8 + p) * 16 + q] * core1[(q * 32 + jj) * 9 + r];
  }
  int og = o / 9, j = o - og * 9;
  Wt[k * 96 + og * 12 + j] = acc;
}

// ---------------------------------------------------------------------------
// Kernel 2: tt GEMM (unchanged from R3, ~13us).
// ---------------------------------------------------------------------------
__global__ __launch_bounds__(512) void tt_gemm2(
    const float* __restrict__ x,       // (2048,1024)
    const float* __restrict__ Wt,      // (1024,96) padded
    const float* __restrict__ bias,    // (72,)
    float* __restrict__ ttout) {       // (2048,72)
  __shared__ __align__(16) float ws[128 * 96];
  __shared__ __align__(16) float xs[8 * 132];
  __shared__ float part[16 * 8 * 73];
  const int t = threadIdx.x;
  const int row0 = blockIdx.x * 8;
  const int kk = t >> 5;
  const int rp = (t >> 3) & 3;
  const int og = t & 7;
  const int r0 = rp * 2;

  float a0[9], a1[9];
#pragma unroll
  for (int j = 0; j < 9; ++j) { a0[j] = 0.f; a1[j] = 0.f; }

  for (int s = 0; s < 8; ++s) {
    __syncthreads();
    const float4* Wg = (const float4*)(Wt + s * 128 * 96);
#pragma unroll
    for (int i = 0; i < 6; ++i) {
      const int idx = i * 512 + t;
      ((float4*)ws)[idx] = Wg[idx];
    }
    if (t < 256) {
      const int rr = t >> 5, j4 = t & 31;
      *(float4*)&xs[rr * 132 + j4 * 4] =
          *(const float4*)(x + (size_t)(row0 + rr) * 1024 + s * 128 + j4 * 4);
    }
    __syncthreads();
#pragma unroll
    for (int i = 0; i < 8; ++i) {
      const int k = kk + i * 16;
      const float4 wA = *(const float4*)&ws[k * 96 + og * 12];
      const float4 wB = *(const float4*)&ws[k * 96 + og * 12 + 4];
      const float w8 = ws[k * 96 + og * 12 + 8];
      const float x0v = xs[r0 * 132 + k];
      const float x1v = xs[r0 * 132 + 132 + k];
      a0[0] += x0v * wA.x; a0[1] += x0v * wA.y;
      a0[2] += x0v * wA.z; a0[3] += x0v * wA.w;
      a0[4] += x0v * wB.x; a0[5] += x0v * wB.y;
      a0[6] += x0v * wB.z; a0[7] += x0v * wB.w;
      a0[8] += x0v * w8;
      a1[0] += x1v * wA.x; a1[1] += x1v * wA.y;
      a1[2] += x1v * wA.z; a1[3] += x1v * wA.w;
      a1[4] += x1v * wB.x; a1[5] += x1v * wB.y;
      a1[6] += x1v * wB.z; a1[7] += x1v * wB.w;
      a1[8] += x1v * w8;
    }
  }

#pragma unroll
  for (int j = 0; j < 9; ++j) {
    part[(kk * 8 + r0) * 73 + og * 9 + j] = a0[j];
    part[(kk * 8 + r0 + 1) * 73 + og * 9 + j] = a1[j];
  }
  __syncthreads();

  for (int i = t; i < 576; i += 512) {
    const int r = i / 72, o = i - r * 72;
    float ssum = bias[o];
#pragma unroll
    for (int kq = 0; kq < 16; ++kq) ssum += part[(kq * 8 + r) * 73 + o];
    ttout[(size_t)(row0 + r) * 72 + o] = ssum;
  }
}

// ---------------------------------------------------------------------------
// Packed single-qubit gate on SoA pack-of-2 state.
//   Pack j holds amps (2j, 2j^3): R[j]=(re_lo, re_hi), I[j]=(im_lo, im_hi).
//   Storage index s = (t<<4) | r.  Pairing s <-> s^MASK; branch = par(ROW&s).
//   SU(2): U = [[u00, u01], [-conj(u01), conj(u00)]].
// ---------------------------------------------------------------------------
template <int MASK, int ROW>
__device__ __forceinline__ void gate_pk(f2 R[8], f2 I[8],
    float u00r, float u00i, float u01r, float u01i,
    f2* __restrict__ buf, int t) {
  constexpr int RM = MASK & 15;
  constexpr int TM = (MASK >> 4) & 0xFF;
  constexpr int LM = TM & 63;
  constexpr bool LDSX = (TM & 0xC0) != 0;
  constexpr int FLIP = parity12(ROW & 3);                 // hi-half parity offset
  constexpr int JX = (RM == 0) ? 0 : (((RM & 1) ? (RM ^ 3) : RM) >> 1);
  constexpr bool SW = (RM & 1) != 0;                      // partner pack half-swap

  // thread-level parity folded into two sign flips (SU(2) structure)
  const int tsgn = (__popc(ROW & (t << 4)) & 1) << 31;
  const float dEi = __int_as_float(__float_as_int(u00i) ^ tsgn);
  const float oEr = __int_as_float(__float_as_int(u01r) ^ tsgn);
  const float ndEi = -dEi, noEr = -oEr;
  const f2 A  = mk2(u00r, u00r);
  const f2 C  = mk2(u01i, u01i);
  const f2 nC = mk2(-u01i, -u01i);

  auto Dof = [&](int pe, int ph) { return mk2(pe ? ndEi : dEi, ph ? ndEi : dEi); };
  auto Oof = [&](int pe, int ph) { return mk2(pe ? noEr : oEr, ph ? noEr : oEr); };

  // nr = u00r*ar -+ dEi*ai +- oEr*br - u01i*bi ; ni = +-dEi*ar + u00r*ai + u01i*br +- oEr*bi
  auto upd = [&](int j, f2 Rb, f2 Ib, f2& outR, f2& outI) {
    const int pe = parity12(ROW & (2 * j));
    const int ph = pe ^ FLIP;
    const f2 Dj = Dof(pe, ph), nDj = Dof(!pe, !ph), Oj = Oof(pe, ph);
    const f2 a = R[j], ii = I[j];
    outR = pkfma(A, a, pkfma(nDj, ii, pkfma(Oj, Rb, pkmul(nC, Ib))));
    outI = pkfma(Dj, a, pkfma(A, ii, pkfma(C, Rb, pkmul(Oj, Ib))));
  };

  if constexpr (LDSX) {
    const int tp = t ^ TM;
    // phase 0: packs {0,1,6,7}; phase 1: packs {2,3,4,5} (closed under j^JX)
#pragma unroll
    for (int ph2 = 0; ph2 < 2; ++ph2) {
      __syncthreads();
#pragma unroll
      for (int j = 0; j < 8; ++j) {
        const bool inA = (j < 2) || (j > 5);
        if ((ph2 == 0) == inA) {
          const int slot = inA ? ((j < 2) ? j : j - 4) : (j - 2);
          buf[slot * 512 + t] = R[j];
          buf[slot * 512 + 256 + t] = I[j];
        }
      }
      __syncthreads();
#pragma unroll
      for (int j = 0; j < 8; ++j) {
        const bool inA = (j < 2) || (j > 5);
        if ((ph2 == 0) == inA) {
          const int j2 = j ^ JX;
          const bool inA2 = (j2 < 2) || (j2 > 5);
          const int slot2 = inA2 ? ((j2 < 2) ? j2 : j2 - 4) : (j2 - 2);
          f2 Rb = buf[slot2 * 512 + tp];
          f2 Ib = buf[slot2 * 512 + 256 + tp];
          if constexpr (SW) { Rb = swap2(Rb); Ib = swap2(Ib); }
          upd(j, Rb, Ib, R[j], I[j]);
        }
      }
    }
  } else if constexpr (LM != 0) {
#pragma unroll
    for (int j = 0; j < 8; ++j) {
      const f2 Rb = shfl_xor2(R[j], LM);
      const f2 Ib = shfl_xor2(I[j], LM);
      upd(j, Rb, Ib, R[j], I[j]);
    }
  } else {
    // pure register gate: pack pairs (j, j^JX)
#pragma unroll
    for (int j = 0; j < 8; ++j) {
      const int j2 = j ^ JX;
      if (j < j2) {
        f2 Rb1 = R[j2], Ib1 = I[j2], Rb2 = R[j], Ib2 = I[j];
        if constexpr (SW) {
          Rb1 = swap2(Rb1); Ib1 = swap2(Ib1);
          Rb2 = swap2(Rb2); Ib2 = swap2(Ib2);
        }
        f2 nR1, nI1, nR2, nI2;
        upd(j, Rb1, Ib1, nR1, nI1);
        upd(j2, Rb2, Ib2, nR2, nI2);
        R[j] = nR1; I[j] = nI1; R[j2] = nR2; I[j2] = nI2;
      }
    }
  }
}

// ---------------------------------------------------------------------------
// Kernel 3: statevector sim, packed-f32 version.
// ---------------------------------------------------------------------------
__global__ __launch_bounds__(256, 5) void vqc_kernel4(
    const float* __restrict__ x,        // (2048,1024) -- only first 12 cols used
    const float* __restrict__ ttout,    // (2048,72)
    const float* __restrict__ gang,     // (2,12,3)
    float* __restrict__ out) {          // (2048,12)
  const int b = blockIdx.x;
  const int t = threadIdx.x;

  __shared__ __align__(16) f2 buf[2048];       // 16 KiB exchange buffer
  __shared__ float sU[12][4];                  // layer-1: u00r,u00i,u01r,u01i
  __shared__ float sFre[12][2], sFim[12][2];   // layer-0 product vectors

  const float* ttb = ttout + (size_t)b * 72;

  if (t < 24) {
    const int w = (t < 12) ? t : t - 12;
    const int k = (t < 12) ? 1 : 0;
    const int gbase = (k * 12 + w) * 3;
    const int tbase = k * 36 + w * 3;
    float a0 = gang[gbase + 0] + ttb[tbase + 0];
    float a1 = gang[gbase + 1] + ttb[tbase + 1];
    float a2 = gang[gbase + 2] + ttb[tbase + 2];
    float cx = cosf(0.5f * a0), sx = sinf(0.5f * a0);
    float cy = cosf(0.5f * a1), sy = sinf(0.5f * a1);
    float cz = cosf(0.5f * a2), sz = sinf(0.5f * a2);
    float m00r = cy * cx,   m00i = sy * sx;
    float m01r = -sy * cx,  m01i = -cy * sx;
    float m10r = sy * cx,   m10i = -cy * sx;
    float m11r = cy * cx,   m11i = -sy * sx;
    float U00r = cz * m00r + sz * m00i, U00i = cz * m00i - sz * m00r;
    float U01r = cz * m01r + sz * m01i, U01i = cz * m01i - sz * m01r;
    float U10r = cz * m10r - sz * m10i, U10i = cz * m10i + sz * m10r;
    float U11r = cz * m11r - sz * m11i, U11i = cz * m11i + sz * m11r;
    if (t < 12) {
      sU[w][0] = U00r; sU[w][1] = U00i;
      sU[w][2] = U01r; sU[w][3] = U01i;
    } else {
      const float e = x[(size_t)b * 1024 + w] * 0.5f;
      const float c = cosf(e), s = sinf(e);
      sFre[w][0] = U00r * c + U01r * s;  sFim[w][0] = U00i * c + U01i * s;
      sFre[w][1] = U10r * c + U11r * s;  sFim[w][1] = U10i * c + U11i * s;
    }
  }
  __syncthreads();

  // --- product-state init in the B basis (scalar; ~3% of work) ---
  float vr[16], vi[16];
  {
    const int bits[7] = {(t >> 7) & 1,
                         ((t >> 6) ^ (t >> 5)) & 1,
                         ((t >> 5) ^ (t >> 4)) & 1,
                         ((t >> 4) ^ (t >> 3)) & 1,
                         ((t >> 3) ^ (t >> 2)) & 1,
                         ((t >> 2) ^ (t >> 1)) & 1,
                         ((t >> 1) ^ t) & 1};
    float br_ = 1.f, bi_ = 0.f;
#pragma unroll
    for (int w = 0; w < 7; ++w) {
      const float fr = sFre[w][bits[w]], fi = sFim[w][bits[w]];
      const float nr = br_ * fr - bi_ * fi;
      const float ni = br_ * fi + bi_ * fr;
      br_ = nr; bi_ = ni;
    }
    const int t0 = t & 1;
    float b7r[2], b7i[2];
#pragma unroll
    for (int r3 = 0; r3 < 2; ++r3) {
      const float fr = sFre[7][t0 ^ r3], fi = sFim[7][t0 ^ r3];
      b7r[r3] = br_ * fr - bi_ * fi;
      b7i[r3] = br_ * fi + bi_ * fr;
    }
    float hr[8], hi[8];
#pragma unroll
    for (int j = 0; j < 8; ++j) {
      const int r3 = j >> 2, r2 = (j >> 1) & 1, r1 = j & 1;
      const float ar = sFre[8][r3 ^ r2], ai = sFim[8][r3 ^ r2];
      const float cr = sFre[9][r2 ^ r1], ci = sFim[9][r2 ^ r1];
      hr[j] = ar * cr - ai * ci; hi[j] = ar * ci + ai * cr;
    }
    float gr[4], gi[4];
#pragma unroll
    for (int j = 0; j < 4; ++j) {
      const int r1 = j >> 1, r0 = j & 1;
      const float ar = sFre[10][r1 ^ r0], ai = sFim[10][r1 ^ r0];
      const float cr = sFre[11][r0], ci = sFim[11][r0];
      gr[j] = ar * cr - ai * ci; gi[j] = ar * ci + ai * cr;
    }
#pragma unroll
    for (int r = 0; r < 16; ++r) {
      const int r3 = r >> 3, hj = r >> 1, gj = r & 3;
      const float pr = hr[hj] * gr[gj] - hi[hj] * gi[gj];
      const float pi = hr[hj] * gi[gj] + hi[hj] * gr[gj];
      vr[r] = b7r[r3] * pr - b7i[r3] * pi;
      vi[r] = b7r[r3] * pi + b7i[r3] * pr;
    }
  }
  // pack into SoA pairs: pack j = amps (2j, 2j^3)
  f2 R[8], I[8];
#pragma unroll
  for (int j = 0; j < 8; ++j) {
    R[j] = mk2(vr[2 * j], vr[(2 * j) ^ 3]);
    I[j] = mk2(vi[2 * j], vi[(2 * j) ^ 3]);
  }

#define GATE(MASK, ROW, GID) \
  gate_pk<MASK, ROW>(R, I, sU[GID][0], sU[GID][1], sU[GID][2], sU[GID][3], buf, t)

  GATE(0xC00, 0x400, 0);    // w=0   LDS (wave bits)
  GATE(0x200, 0xE00, 1);    // w=1   shfl 0x20
  GATE(0x100, 0xD00, 2);    // w=2   shfl 0x10
  GATE(0x080, 0xC80, 3);    // w=3   shfl 8
  GATE(0x040, 0xC40, 4);    // w=4   shfl 4
  GATE(0x020, 0xC20, 5);    // w=5   shfl 2
  GATE(0x010, 0xC10, 6);    // w=6   shfl 1
  GATE(0x008, 0xC08, 7);    // w=7   reg 8
  GATE(0x004, 0xC04, 8);    // w=8   reg 4
  GATE(0x002, 0xC02, 9);    // w=9   reg 2
  GATE(0x001, 0xC01, 10);   // w=10  reg 1 (half-swap)
  GATE(0xBFF, 0xC00, 11);   // w=11  LDS + lane + reg (half-swap)
#undef GATE

  // ---- measurement: sign(w, s) = parity(MROWS[w] & s), packed ----
  constexpr int MROWS[12] = {0xFFF, 0xA00, 0x700, 0xB80, 0x7C0, 0xBE0,
                             0x7F0, 0xBF8, 0x7FC, 0xBFE, 0x7FF, 0xBFF};
  const f2 Spp = mk2(1.f, 1.f),  Smm = mk2(-1.f, -1.f);
  const f2 Spm = mk2(1.f, -1.f), Smp = mk2(-1.f, 1.f);
  f2 acc2[12];
#pragma unroll
  for (int w = 0; w < 12; ++w) acc2[w] = mk2(0.f, 0.f);
#pragma unroll
  for (int j = 0; j < 8; ++j) {
    const f2 pr2 = pkfma(I[j], I[j], pkmul(R[j], R[j]));
#pragma unroll
    for (int w = 0; w < 12; ++w) {
      const int sl = parity12(MROWS[w] & (2 * j));
      const int sh = sl ^ parity12(MROWS[w] & 3);
      const f2 S = sl ? (sh ? Smm : Smp) : (sh ? Spm : Spp);
      acc2[w] = pkfma(S, pr2, acc2[w]);
    }
  }
  __syncthreads();                       // gate-11 buf reads done
  float* rbuf = (float*)buf;
#pragma unroll
  for (int w = 0; w < 12; ++w) {
    float v = acc2[w].x + acc2[w].y;
    if (__popc(MROWS[w] & (t << 4)) & 1) v = -v;
#pragma unroll
    for (int off = 32; off > 0; off >>= 1) v += __shfl_down(v, off, 64);
    if ((t & 63) == 0) rbuf[(t >> 6) * 12 + w] = v;
  }
  __syncthreads();
  if (t < 12) {
    out[(size_t)b * 12 + t] = rbuf[t] + rbuf[12 + t] + rbuf[24 + t] + rbuf[36 + t];
  }
}

// ---------------------------------------------------------------------------
extern "C" void kernel_launch(void* const* d_in, const int* in_sizes, int n_in,
                              void* d_out, int out_size, void* d_ws, size_t ws_size,
                              hipStream_t stream) {
  const float* x       = (const float*)d_in[0];
  const float* core0   = (const float*)d_in[1];
  const float* core1   = (const float*)d_in[2];
  const float* tt_bias = (const float*)d_in[3];
  const float* gang    = (const float*)d_in[4];
  float* out = (float*)d_out;
  float* Wt     = (float*)d_ws;                 // 1024*96 floats = 384 KiB
  float* ttout  = (float*)d_ws + 98304;         // 2048*72 floats = 576 KiB

  const int bsz = in_sizes[0] / 1024;  // 2048

  build_w_kernel<<<288, 256, 0, stream>>>(core0, core1, Wt);
  tt_gemm2<<<bsz / 8, 512, 0, stream>>>(x, Wt, tt_bias, ttout);
  vqc_kernel4<<<bsz, 256, 0, stream>>>(x, ttout, gang, out);
}

// Round 6
// 54.605 us; speedup vs baseline: 3.6413x; 1.0766x over previous
//
#include <hip/hip_runtime.h>
#include <math.h>

#define N_WIRES 12

__host__ __device__ constexpr int parity12(int x) {
  x ^= x >> 8; x ^= x >> 4; x ^= x >> 2; x ^= x >> 1;
  return x & 1;
}

typedef float2 f2;
__device__ __forceinline__ f2 mk2(float a, float b) { f2 r; r.x = a; r.y = b; return r; }
__device__ __forceinline__ f2 pkmul(f2 a, f2 b) {
  f2 d; asm("v_pk_mul_f32 %0, %1, %2" : "=v"(d) : "v"(a), "v"(b)); return d;
}
__device__ __forceinline__ f2 pkfma(f2 a, f2 b, f2 c) {
  f2 d; asm("v_pk_fma_f32 %0, %1, %2, %3" : "=v"(d) : "v"(a), "v"(b), "v"(c)); return d;
}
__device__ __forceinline__ f2 shfl_xor2(f2 v, int m) {
  f2 r; r.x = __shfl_xor(v.x, m, 64); r.y = __shfl_xor(v.y, m, 64); return r;
}
__device__ __forceinline__ f2 swap2(f2 v) { return mk2(v.y, v.x); }

struct cpx { float r, i; };
__device__ __forceinline__ cpx cmulc(cpx a, cpx b) {
  return {a.r * b.r - a.i * b.i, a.r * b.i + a.i * b.r};
}

// ---------------------------------------------------------------------------
// Kernel 1: fold the two TT cores into W, padded layout (unchanged).
// ---------------------------------------------------------------------------
__global__ __launch_bounds__(256) void build_w_kernel(
    const float* __restrict__ core0,   // (1,32,8,16)
    const float* __restrict__ core1,   // (16,32,9,1)
    float* __restrict__ Wt) {          // (1024,96) padded
  int idx = blockIdx.x * 256 + threadIdx.x;
  int k = idx / 72;
  int o = idx - k * 72;
  int i = k >> 5, jj = k & 31;
  int p = o / 9, r = o - p * 9;
  float acc = 0.f;
#pragma unroll
  for (int q = 0; q < 16; ++q) {
    acc += core0[(i * 8 + p) * 16 + q] * core1[(q * 32 + jj) * 9 + r];
  }
  int og = o / 9, j = o - og * 9;
  Wt[k * 96 + og * 12 + j] = acc;
}

// ---------------------------------------------------------------------------
// Kernel 2: tt GEMM (unchanged).
// ---------------------------------------------------------------------------
__global__ __launch_bounds__(512) void tt_gemm2(
    const float* __restrict__ x,       // (2048,1024)
    const float* __restrict__ Wt,      // (1024,96) padded
    const float* __restrict__ bias,    // (72,)
    float* __restrict__ ttout) {       // (2048,72)
  __shared__ __align__(16) float ws[128 * 96];
  __shared__ __align__(16) float xs[8 * 132];
  __shared__ float part[16 * 8 * 73];
  const int t = threadIdx.x;
  const int row0 = blockIdx.x * 8;
  const int kk = t >> 5;
  const int rp = (t >> 3) & 3;
  const int og = t & 7;
  const int r0 = rp * 2;

  float a0[9], a1[9];
#pragma unroll
  for (int j = 0; j < 9; ++j) { a0[j] = 0.f; a1[j] = 0.f; }

  for (int s = 0; s < 8; ++s) {
    __syncthreads();
    const float4* Wg = (const float4*)(Wt + s * 128 * 96);
#pragma unroll
    for (int i = 0; i < 6; ++i) {
      const int idx = i * 512 + t;
      ((float4*)ws)[idx] = Wg[idx];
    }
    if (t < 256) {
      const int rr = t >> 5, j4 = t & 31;
      *(float4*)&xs[rr * 132 + j4 * 4] =
          *(const float4*)(x + (size_t)(row0 + rr) * 1024 + s * 128 + j4 * 4);
    }
    __syncthreads();
#pragma unroll
    for (int i = 0; i < 8; ++i) {
      const int k = kk + i * 16;
      const float4 wA = *(const float4*)&ws[k * 96 + og * 12];
      const float4 wB = *(const float4*)&ws[k * 96 + og * 12 + 4];
      const float w8 = ws[k * 96 + og * 12 + 8];
      const float x0v = xs[r0 * 132 + k];
      const float x1v = xs[r0 * 132 + 132 + k];
      a0[0] += x0v * wA.x; a0[1] += x0v * wA.y;
      a0[2] += x0v * wA.z; a0[3] += x0v * wA.w;
      a0[4] += x0v * wB.x; a0[5] += x0v * wB.y;
      a0[6] += x0v * wB.z; a0[7] += x0v * wB.w;
      a0[8] += x0v * w8;
      a1[0] += x1v * wA.x; a1[1] += x1v * wA.y;
      a1[2] += x1v * wA.z; a1[3] += x1v * wA.w;
      a1[4] += x1v * wB.x; a1[5] += x1v * wB.y;
      a1[6] += x1v * wB.z; a1[7] += x1v * wB.w;
      a1[8] += x1v * w8;
    }
  }

#pragma unroll
  for (int j = 0; j < 9; ++j) {
    part[(kk * 8 + r0) * 73 + og * 9 + j] = a0[j];
    part[(kk * 8 + r0 + 1) * 73 + og * 9 + j] = a1[j];
  }
  __syncthreads();

  for (int i = t; i < 576; i += 512) {
    const int r = i / 72, o = i - r * 72;
    float ssum = bias[o];
#pragma unroll
    for (int kq = 0; kq < 16; ++kq) ssum += part[(kq * 8 + r) * 73 + o];
    ttout[(size_t)(row0 + r) * 72 + o] = ssum;
  }
}

// ---------------------------------------------------------------------------
// Packed single-qubit gate; wave-resident state, 32 packs/thread.
//   Storage index s = (lane<<6) | r.  Pack j holds amps (2j, 2j^3).
//   Pairing s <-> s^MASK; branch bit = parity(ROW & s).
//   MASK bits 0-5: register xor; bits 6-11: lane xor (shfl).
//   SU(2): U = [[u00, u01], [-conj(u01), conj(u00)]].
// ---------------------------------------------------------------------------
template <int MASK, int ROW>
__device__ __forceinline__ void gate_pk(f2 R[32], f2 I[32],
    float u00r, float u00i, float u01r, float u01i, int lane) {
  constexpr int RM = MASK & 0x3F;
  constexpr int LM = (MASK >> 6) & 0x3F;
  constexpr int FLIP = parity12(ROW & 3);
  constexpr int JX = (RM == 0) ? 0 : (((RM & 1) ? (RM ^ 3) : RM) >> 1);
  constexpr bool SW = (RM & 1) != 0;

  // thread(lane)-level parity folded into two sign flips (SU(2) structure)
  const int tsgn = (__popc((ROW >> 6) & lane) & 1) << 31;
  const float dEi = __int_as_float(__float_as_int(u00i) ^ tsgn);
  const float oEr = __int_as_float(__float_as_int(u01r) ^ tsgn);
  const float ndEi = -dEi, noEr = -oEr;
  const f2 A  = mk2(u00r, u00r);
  const f2 C  = mk2(u01i, u01i);
  const f2 nC = mk2(-u01i, -u01i);

  auto Dof = [&](int pe, int ph) { return mk2(pe ? ndEi : dEi, ph ? ndEi : dEi); };
  auto Oof = [&](int pe, int ph) { return mk2(pe ? noEr : oEr, ph ? noEr : oEr); };

  auto upd = [&](int j, f2 Rb, f2 Ib, f2& outR, f2& outI) {
    const int pe = parity12(ROW & (2 * j));
    const int ph = pe ^ FLIP;
    const f2 Dj = Dof(pe, ph), nDj = Dof(!pe, !ph), Oj = Oof(pe, ph);
    const f2 a = R[j], ii = I[j];
    outR = pkfma(A, a, pkfma(nDj, ii, pkfma(Oj, Rb, pkmul(nC, Ib))));
    outI = pkfma(Dj, a, pkfma(A, ii, pkfma(C, Rb, pkmul(Oj, Ib))));
  };

  if constexpr (LM != 0 && RM == 0) {
    // pure lane gate: partner is same pack in lane^LM
#pragma unroll
    for (int j = 0; j < 32; ++j) {
      const f2 Rb = shfl_xor2(R[j], LM);
      const f2 Ib = shfl_xor2(I[j], LM);
      f2 nR, nI;
      upd(j, Rb, Ib, nR, nI);
      R[j] = nR; I[j] = nI;
    }
  } else if constexpr (LM != 0 && RM != 0) {
    // mixed lane+reg gate: process pack pairs; read all shfls before writes
#pragma unroll
    for (int j = 0; j < 32; ++j) {
      const int j2 = j ^ JX;
      if (j < j2) {
        f2 Rb1 = shfl_xor2(R[j2], LM), Ib1 = shfl_xor2(I[j2], LM);
        f2 Rb2 = shfl_xor2(R[j],  LM), Ib2 = shfl_xor2(I[j],  LM);
        if constexpr (SW) {
          Rb1 = swap2(Rb1); Ib1 = swap2(Ib1);
          Rb2 = swap2(Rb2); Ib2 = swap2(Ib2);
        }
        f2 nR1, nI1, nR2, nI2;
        upd(j, Rb1, Ib1, nR1, nI1);
        upd(j2, Rb2, Ib2, nR2, nI2);
        R[j] = nR1; I[j] = nI1; R[j2] = nR2; I[j2] = nI2;
      }
    }
  } else {
    // pure register gate: pack pairs (j, j^JX)
#pragma unroll
    for (int j = 0; j < 32; ++j) {
      const int j2 = j ^ JX;
      if (j < j2) {
        f2 Rb1 = R[j2], Ib1 = I[j2], Rb2 = R[j], Ib2 = I[j];
        if constexpr (SW) {
          Rb1 = swap2(Rb1); Ib1 = swap2(Ib1);
          Rb2 = swap2(Rb2); Ib2 = swap2(Ib2);
        }
        f2 nR1, nI1, nR2, nI2;
        upd(j, Rb1, Ib1, nR1, nI1);
        upd(j2, Rb2, Ib2, nR2, nI2);
        R[j] = nR1; I[j] = nI1; R[j2] = nR2; I[j2] = nI2;
      }
    }
  }
}

// ---------------------------------------------------------------------------
// Kernel 3: statevector sim, one WAVE per batch row. 64 amps/thread,
// no LDS, no barriers. Storage s = (lane<<6)|r; wire-bit of s per B^-1:
//   w0=s11 w1=s10^s9 ... w11=s0  (same basis as R2/R4, new physical split).
// ---------------------------------------------------------------------------
__global__ __launch_bounds__(256, 2) void vqc_kernel5(
    const float* __restrict__ x,        // (2048,1024) -- only first 12 cols used
    const float* __restrict__ ttout,    // (2048,72)
    const float* __restrict__ gang,     // (2,12,3)
    float* __restrict__ out) {          // (2048,12)
  const int t = threadIdx.x;
  const int lane = t & 63;
  const int b = blockIdx.x * 4 + (t >> 6);
  const float* ttb = ttout + (size_t)b * 72;

  // --- lanes 0..11: layer-1 U (wire=lane); lanes 16..27: layer-0 f-vector ---
  float c0 = 0.f, c1 = 0.f, c2 = 0.f, c3 = 0.f;
  const bool uLane = lane < 12;
  const bool fLane = (lane >= 16) && (lane < 28);
  if (uLane || fLane) {
    const int w = uLane ? lane : lane - 16;
    const int k = uLane ? 1 : 0;
    const int gbase = (k * 12 + w) * 3;
    const int tbase = k * 36 + w * 3;
    const float a0 = gang[gbase + 0] + ttb[tbase + 0];
    const float a1 = gang[gbase + 1] + ttb[tbase + 1];
    const float a2 = gang[gbase + 2] + ttb[tbase + 2];
    const float cx = cosf(0.5f * a0), sx = sinf(0.5f * a0);
    const float cy = cosf(0.5f * a1), sy = sinf(0.5f * a1);
    const float cz = cosf(0.5f * a2), sz = sinf(0.5f * a2);
    // M = Ry @ Rx ; U = Rz @ M
    const float m00r = cy * cx,   m00i = sy * sx;
    const float m01r = -sy * cx,  m01i = -cy * sx;
    const float m10r = sy * cx,   m10i = -cy * sx;
    const float m11r = cy * cx,   m11i = -sy * sx;
    const float U00r = cz * m00r + sz * m00i, U00i = cz * m00i - sz * m00r;
    const float U01r = cz * m01r + sz * m01i, U01i = cz * m01i - sz * m01r;
    const float U10r = cz * m10r - sz * m10i, U10i = cz * m10i + sz * m10r;
    const float U11r = cz * m11r - sz * m11i, U11i = cz * m11i + sz * m11r;
    if (uLane) {
      c0 = U00r; c1 = U00i; c2 = U01r; c3 = U01i;
    } else {
      const float e = x[(size_t)b * 1024 + w] * 0.5f;
      const float cc = cosf(e), ss = sinf(e);
      c0 = U00r * cc + U01r * ss;  c1 = U00i * cc + U01i * ss;
      c2 = U10r * cc + U11r * ss;  c3 = U10i * cc + U11i * ss;
    }
  }

  // --- broadcast layer-0 product vectors to all lanes ---
  float Fr[12][2], Fi[12][2];
#pragma unroll
  for (int w = 0; w < 12; ++w) {
    Fr[w][0] = __shfl(c0, 16 + w, 64);
    Fi[w][0] = __shfl(c1, 16 + w, 64);
    Fr[w][1] = __shfl(c2, 16 + w, 64);
    Fi[w][1] = __shfl(c3, 16 + w, 64);
  }

  // --- product-state init in B basis ---
  // lane-bit wires: w0=l5, w1=l4^l3, w2=l3^l2, w3=l2^l1, w4=l1^l0
  // reg-crossing:   w5=l0^r5, w6=r5^r4, ..., w10=r1^r0, w11=r0
  const int bw0 = (lane >> 5) & 1;
  const int bw1 = ((lane >> 4) ^ (lane >> 3)) & 1;
  const int bw2 = ((lane >> 3) ^ (lane >> 2)) & 1;
  const int bw3 = ((lane >> 2) ^ (lane >> 1)) & 1;
  const int bw4 = ((lane >> 1) ^ lane) & 1;
  const int l0 = lane & 1;

  cpx P = {bw0 ? Fr[0][1] : Fr[0][0], bw0 ? Fi[0][1] : Fi[0][0]};
  P = cmulc(P, {bw1 ? Fr[1][1] : Fr[1][0], bw1 ? Fi[1][1] : Fi[1][0]});
  P = cmulc(P, {bw2 ? Fr[2][1] : Fr[2][0], bw2 ? Fi[2][1] : Fi[2][0]});
  P = cmulc(P, {bw3 ? Fr[3][1] : Fr[3][0], bw3 ? Fi[3][1] : Fi[3][0]});
  P = cmulc(P, {bw4 ? Fr[4][1] : Fr[4][0], bw4 ? Fi[4][1] : Fi[4][0]});

  cpx A1[2];
  A1[0] = {l0 ? Fr[5][1] : Fr[5][0], l0 ? Fi[5][1] : Fi[5][0]};
  A1[1] = {l0 ? Fr[5][0] : Fr[5][1], l0 ? Fi[5][0] : Fi[5][1]};
  cpx A2[4];
#pragma unroll
  for (int a = 0; a < 2; ++a)
#pragma unroll
    for (int bb = 0; bb < 2; ++bb)
      A2[a * 2 + bb] = cmulc(A1[a], {Fr[6][a ^ bb], Fi[6][a ^ bb]});
  cpx A3[8];
#pragma unroll
  for (int i = 0; i < 4; ++i)
#pragma unroll
    for (int bb = 0; bb < 2; ++bb)
      A3[i * 2 + bb] = cmulc(A2[i], {Fr[7][(i & 1) ^ bb], Fi[7][(i & 1) ^ bb]});
  cpx A4[16];
#pragma unroll
  for (int i = 0; i < 8; ++i)
#pragma unroll
    for (int bb = 0; bb < 2; ++bb)
      A4[i * 2 + bb] = cmulc(A3[i], {Fr[8][(i & 1) ^ bb], Fi[8][(i & 1) ^ bb]});

  cpx T2[4];
#pragma unroll
  for (int j = 0; j < 4; ++j)
    T2[j] = cmulc({Fr[10][(j >> 1) ^ (j & 1)], Fi[10][(j >> 1) ^ (j & 1)]},
                  {Fr[11][j & 1], Fi[11][j & 1]});
  cpx TP[8];
#pragma unroll
  for (int r2 = 0; r2 < 2; ++r2)
#pragma unroll
    for (int j = 0; j < 4; ++j)
      TP[r2 * 4 + j] = cmulc(P,
          cmulc({Fr[9][r2 ^ (j >> 1)], Fi[9][r2 ^ (j >> 1)]}, T2[j]));

  // fill packs: pack j = amps (2j, 2j^3); A4 idx = j>>1; T idx per low bits
  f2 R[32], I[32];
#pragma unroll
  for (int j = 0; j < 32; ++j) {
    const cpx Av = A4[j >> 1];
    const int lo = (((j >> 1) & 1) << 2) | ((j & 1) << 1);
    const int hi = (((j >> 1) & 1) << 2) | (((j & 1) ^ 1) << 1) | 1;
    const f2 Tre = mk2(TP[lo].r, TP[hi].r);
    const f2 Tim = mk2(TP[lo].i, TP[hi].i);
    const f2 Ar = mk2(Av.r, Av.r);
    R[j] = pkfma(mk2(-Av.i, -Av.i), Tim, pkmul(Ar, Tre));
    I[j] = pkfma(mk2(Av.i, Av.i), Tre, pkmul(Ar, Tim));
  }

#define GATE(MASK, ROW, G)                                                  \
  gate_pk<MASK, ROW>(R, I, __shfl(c0, G, 64), __shfl(c1, G, 64),            \
                     __shfl(c2, G, 64), __shfl(c3, G, 64), lane)

  // ---- layer 1 in B basis (layer 0 folded into init) ----
  GATE(0xC00, 0x400, 0);    // w=0   lane xor 0x30
  GATE(0x200, 0xE00, 1);    // w=1   lane xor 0x08
  GATE(0x100, 0xD00, 2);    // w=2   lane xor 0x04
  GATE(0x080, 0xC80, 3);    // w=3   lane xor 0x02
  GATE(0x040, 0xC40, 4);    // w=4   lane xor 0x01
  GATE(0x020, 0xC20, 5);    // w=5   reg 0x20
  GATE(0x010, 0xC10, 6);    // w=6   reg 0x10
  GATE(0x008, 0xC08, 7);    // w=7   reg 8
  GATE(0x004, 0xC04, 8);    // w=8   reg 4
  GATE(0x002, 0xC02, 9);    // w=9   reg 2
  GATE(0x001, 0xC01, 10);   // w=10  reg 1 (half-swap)
  GATE(0xBFF, 0xC00, 11);   // w=11  lane 0x2F + reg 0x3F (half-swap)
#undef GATE

  // ---- measurement: sign(w, s) = parity(MROWS[w] & s), packed ----
  constexpr int MROWS[12] = {0xFFF, 0xA00, 0x700, 0xB80, 0x7C0, 0xBE0,
                             0x7F0, 0xBF8, 0x7FC, 0xBFE, 0x7FF, 0xBFF};
  const f2 Spp = mk2(1.f, 1.f),  Smm = mk2(-1.f, -1.f);
  const f2 Spm = mk2(1.f, -1.f), Smp = mk2(-1.f, 1.f);
  f2 acc2[12];
#pragma unroll
  for (int w = 0; w < 12; ++w) acc2[w] = mk2(0.f, 0.f);
#pragma unroll
  for (int j = 0; j < 32; ++j) {
    const f2 pr2 = pkfma(I[j], I[j], pkmul(R[j], R[j]));
#pragma unroll
    for (int w = 0; w < 12; ++w) {
      const int sl = parity12(MROWS[w] & (2 * j));
      const int sh = sl ^ parity12(MROWS[w] & 3);
      const f2 S = sl ? (sh ? Smm : Smp) : (sh ? Spm : Spp);
      acc2[w] = pkfma(S, pr2, acc2[w]);
    }
  }
#pragma unroll
  for (int w = 0; w < 12; ++w) {
    float v = acc2[w].x + acc2[w].y;
    if (__popc((MROWS[w] >> 6) & lane) & 1) v = -v;
#pragma unroll
    for (int off = 32; off > 0; off >>= 1) v += __shfl_down(v, off, 64);
    if (lane == 0) out[(size_t)b * 12 + w] = v;
  }
}

// ---------------------------------------------------------------------------
extern "C" void kernel_launch(void* const* d_in, const int* in_sizes, int n_in,
                              void* d_out, int out_size, void* d_ws, size_t ws_size,
                              hipStream_t stream) {
  const float* x       = (const float*)d_in[0];
  const float* core0   = (const float*)d_in[1];
  const float* core1   = (const float*)d_in[2];
  const float* tt_bias = (const float*)d_in[3];
  const float* gang    = (const float*)d_in[4];
  float* out = (float*)d_out;
  float* Wt     = (float*)d_ws;                 // 1024*96 floats = 384 KiB
  float* ttout  = (float*)d_ws + 98304;         // 2048*72 floats = 576 KiB

  const int bsz = in_sizes[0] / 1024;  // 2048

  build_w_kernel<<<288, 256, 0, stream>>>(core0, core1, Wt);
  tt_gemm2<<<bsz / 8, 512, 0, stream>>>(x, Wt, tt_bias, ttout);
  vqc_kernel5<<<bsz / 4, 256, 0, stream>>>(x, ttout, gang, out);
}

// Round 7
// 54.123 us; speedup vs baseline: 3.6738x; 1.0089x over previous
//
#include <hip/hip_runtime.h>
#include <math.h>

#define N_WIRES 12

__host__ __device__ constexpr int parity12(int x) {
  x ^= x >> 8; x ^= x >> 4; x ^= x >> 2; x ^= x >> 1;
  return x & 1;
}

typedef float2 f2;
__device__ __forceinline__ f2 mk2(float a, float b) { f2 r; r.x = a; r.y = b; return r; }
__device__ __forceinline__ f2 pkmul(f2 a, f2 b) {
  f2 d; asm("v_pk_mul_f32 %0, %1, %2" : "=v"(d) : "v"(a), "v"(b)); return d;
}
__device__ __forceinline__ f2 pkfma(f2 a, f2 b, f2 c) {
  f2 d; asm("v_pk_fma_f32 %0, %1, %2, %3" : "=v"(d) : "v"(a), "v"(b), "v"(c)); return d;
}
__device__ __forceinline__ f2 shfl_xor2(f2 v, int m) {
  f2 r; r.x = __shfl_xor(v.x, m, 64); r.y = __shfl_xor(v.y, m, 64); return r;
}
__device__ __forceinline__ f2 swap2(f2 v) { return mk2(v.y, v.x); }

struct cpx { float r, i; };
__device__ __forceinline__ cpx cmulc(cpx a, cpx b) {
  return {a.r * b.r - a.i * b.i, a.r * b.i + a.i * b.r};
}

// ---------------------------------------------------------------------------
// Kernel 1: fold the two TT cores into W, padded layout (unchanged).
// ---------------------------------------------------------------------------
__global__ __launch_bounds__(256) void build_w_kernel(
    const float* __restrict__ core0,   // (1,32,8,16)
    const float* __restrict__ core1,   // (16,32,9,1)
    float* __restrict__ Wt) {          // (1024,96) padded
  int idx = blockIdx.x * 256 + threadIdx.x;
  int k = idx / 72;
  int o = idx - k * 72;
  int i = k >> 5, jj = k & 31;
  int p = o / 9, r = o - p * 9;
  float acc = 0.f;
#pragma unroll
  for (int q = 0; q < 16; ++q) {
    acc += core0[(i * 8 + p) * 16 + q] * core1[(q * 32 + jj) * 9 + r];
  }
  int og = o / 9, j = o - og * 9;
  Wt[k * 96 + og * 12 + j] = acc;
}

// ---------------------------------------------------------------------------
// Kernel 2: tt GEMM (unchanged).
// ---------------------------------------------------------------------------
__global__ __launch_bounds__(512) void tt_gemm2(
    const float* __restrict__ x,       // (2048,1024)
    const float* __restrict__ Wt,      // (1024,96) padded
    const float* __restrict__ bias,    // (72,)
    float* __restrict__ ttout) {       // (2048,72)
  __shared__ __align__(16) float ws[128 * 96];
  __shared__ __align__(16) float xs[8 * 132];
  __shared__ float part[16 * 8 * 73];
  const int t = threadIdx.x;
  const int row0 = blockIdx.x * 8;
  const int kk = t >> 5;
  const int rp = (t >> 3) & 3;
  const int og = t & 7;
  const int r0 = rp * 2;

  float a0[9], a1[9];
#pragma unroll
  for (int j = 0; j < 9; ++j) { a0[j] = 0.f; a1[j] = 0.f; }

  for (int s = 0; s < 8; ++s) {
    __syncthreads();
    const float4* Wg = (const float4*)(Wt + s * 128 * 96);
#pragma unroll
    for (int i = 0; i < 6; ++i) {
      const int idx = i * 512 + t;
      ((float4*)ws)[idx] = Wg[idx];
    }
    if (t < 256) {
      const int rr = t >> 5, j4 = t & 31;
      *(float4*)&xs[rr * 132 + j4 * 4] =
          *(const float4*)(x + (size_t)(row0 + rr) * 1024 + s * 128 + j4 * 4);
    }
    __syncthreads();
#pragma unroll
    for (int i = 0; i < 8; ++i) {
      const int k = kk + i * 16;
      const float4 wA = *(const float4*)&ws[k * 96 + og * 12];
      const float4 wB = *(const float4*)&ws[k * 96 + og * 12 + 4];
      const float w8 = ws[k * 96 + og * 12 + 8];
      const float x0v = xs[r0 * 132 + k];
      const float x1v = xs[r0 * 132 + 132 + k];
      a0[0] += x0v * wA.x; a0[1] += x0v * wA.y;
      a0[2] += x0v * wA.z; a0[3] += x0v * wA.w;
      a0[4] += x0v * wB.x; a0[5] += x0v * wB.y;
      a0[6] += x0v * wB.z; a0[7] += x0v * wB.w;
      a0[8] += x0v * w8;
      a1[0] += x1v * wA.x; a1[1] += x1v * wA.y;
      a1[2] += x1v * wA.z; a1[3] += x1v * wA.w;
      a1[4] += x1v * wB.x; a1[5] += x1v * wB.y;
      a1[6] += x1v * wB.z; a1[7] += x1v * wB.w;
      a1[8] += x1v * w8;
    }
  }

#pragma unroll
  for (int j = 0; j < 9; ++j) {
    part[(kk * 8 + r0) * 73 + og * 9 + j] = a0[j];
    part[(kk * 8 + r0 + 1) * 73 + og * 9 + j] = a1[j];
  }
  __syncthreads();

  for (int i = t; i < 576; i += 512) {
    const int r = i / 72, o = i - r * 72;
    float ssum = bias[o];
#pragma unroll
    for (int kq = 0; kq < 16; ++kq) ssum += part[(kq * 8 + r) * 73 + o];
    ttout[(size_t)(row0 + r) * 72 + o] = ssum;
  }
}

// ---------------------------------------------------------------------------
// Packed single-qubit gate; wave-resident state, 32 packs/thread.
//   Storage index s = (lane<<6) | r.  Pack j holds amps (2j, 2j^3).
//   Pairing s <-> s^MASK; branch bit = parity(ROW & s).
//   MASK bits 0-5: register xor; bits 6-11: lane xor (shfl).
//   SU(2): U = [[u00, u01], [-conj(u01), conj(u00)]].  (unchanged from R5)
// ---------------------------------------------------------------------------
template <int MASK, int ROW>
__device__ __forceinline__ void gate_pk(f2 R[32], f2 I[32],
    float u00r, float u00i, float u01r, float u01i, int lane) {
  constexpr int RM = MASK & 0x3F;
  constexpr int LM = (MASK >> 6) & 0x3F;
  constexpr int FLIP = parity12(ROW & 3);
  constexpr int JX = (RM == 0) ? 0 : (((RM & 1) ? (RM ^ 3) : RM) >> 1);
  constexpr bool SW = (RM & 1) != 0;

  const int tsgn = (__popc((ROW >> 6) & lane) & 1) << 31;
  const float dEi = __int_as_float(__float_as_int(u00i) ^ tsgn);
  const float oEr = __int_as_float(__float_as_int(u01r) ^ tsgn);
  const float ndEi = -dEi, noEr = -oEr;
  const f2 A  = mk2(u00r, u00r);
  const f2 C  = mk2(u01i, u01i);
  const f2 nC = mk2(-u01i, -u01i);

  auto Dof = [&](int pe, int ph) { return mk2(pe ? ndEi : dEi, ph ? ndEi : dEi); };
  auto Oof = [&](int pe, int ph) { return mk2(pe ? noEr : oEr, ph ? noEr : oEr); };

  auto upd = [&](int j, f2 Rb, f2 Ib, f2& outR, f2& outI) {
    const int pe = parity12(ROW & (2 * j));
    const int ph = pe ^ FLIP;
    const f2 Dj = Dof(pe, ph), nDj = Dof(!pe, !ph), Oj = Oof(pe, ph);
    const f2 a = R[j], ii = I[j];
    outR = pkfma(A, a, pkfma(nDj, ii, pkfma(Oj, Rb, pkmul(nC, Ib))));
    outI = pkfma(Dj, a, pkfma(A, ii, pkfma(C, Rb, pkmul(Oj, Ib))));
  };

  if constexpr (LM != 0 && RM == 0) {
#pragma unroll
    for (int j = 0; j < 32; ++j) {
      const f2 Rb = shfl_xor2(R[j], LM);
      const f2 Ib = shfl_xor2(I[j], LM);
      f2 nR, nI;
      upd(j, Rb, Ib, nR, nI);
      R[j] = nR; I[j] = nI;
    }
  } else if constexpr (LM != 0 && RM != 0) {
#pragma unroll
    for (int j = 0; j < 32; ++j) {
      const int j2 = j ^ JX;
      if (j < j2) {
        f2 Rb1 = shfl_xor2(R[j2], LM), Ib1 = shfl_xor2(I[j2], LM);
        f2 Rb2 = shfl_xor2(R[j],  LM), Ib2 = shfl_xor2(I[j],  LM);
        if constexpr (SW) {
          Rb1 = swap2(Rb1); Ib1 = swap2(Ib1);
          Rb2 = swap2(Rb2); Ib2 = swap2(Ib2);
        }
        f2 nR1, nI1, nR2, nI2;
        upd(j, Rb1, Ib1, nR1, nI1);
        upd(j2, Rb2, Ib2, nR2, nI2);
        R[j] = nR1; I[j] = nI1; R[j2] = nR2; I[j2] = nI2;
      }
    }
  } else {
#pragma unroll
    for (int j = 0; j < 32; ++j) {
      const int j2 = j ^ JX;
      if (j < j2) {
        f2 Rb1 = R[j2], Ib1 = I[j2], Rb2 = R[j], Ib2 = I[j];
        if constexpr (SW) {
          Rb1 = swap2(Rb1); Ib1 = swap2(Ib1);
          Rb2 = swap2(Rb2); Ib2 = swap2(Ib2);
        }
        f2 nR1, nI1, nR2, nI2;
        upd(j, Rb1, Ib1, nR1, nI1);
        upd(j2, Rb2, Ib2, nR2, nI2);
        R[j] = nR1; I[j] = nI1; R[j2] = nR2; I[j2] = nI2;
      }
    }
  }
}

// ---------------------------------------------------------------------------
// Kernel 3: statevector sim, one WAVE per batch row, 64 amps/thread.
// Init restructured vs R5 to cap register pressure:
//   amp(r) = PT_hi[(r>>3)] * T_lo[r&15]
//   PT_hi[(r5,r4,r3)] = P(lane) * F5[l0^r5] * F6[r5^r4] * F7[r4^r3]   (8 cpx)
//   T_lo[(r3,r2,r1,r0)] = F8[r3^r2]*F9[r2^r1]*F10[r1^r0]*F11[r0]      (16 cpx)
//   P(lane) = prod_{w=0..4} Fw[lane-bit_w]
// Broadcast F factors are consumed on the fly (never materialized).
// Wire-bit map (B basis, identical to R5): w0=l5, w1=l4^l3, w2=l3^l2,
//   w3=l2^l1, w4=l1^l0, w5=l0^r5, w6=r5^r4, ..., w10=r1^r0, w11=r0.
// ---------------------------------------------------------------------------
__global__ __launch_bounds__(256, 2) void vqc_kernel6(
    const float* __restrict__ x,        // (2048,1024) -- only first 12 cols used
    const float* __restrict__ ttout,    // (2048,72)
    const float* __restrict__ gang,     // (2,12,3)
    float* __restrict__ out) {          // (2048,12)
  const int t = threadIdx.x;
  const int lane = t & 63;
  const int b = blockIdx.x * 4 + (t >> 6);
  const float* ttb = ttout + (size_t)b * 72;

  // --- lanes 0..11: layer-1 U (wire=lane); lanes 16..27: layer-0 f-vector ---
  float c0 = 0.f, c1 = 0.f, c2 = 0.f, c3 = 0.f;
  const bool uLane = lane < 12;
  const bool fLane = (lane >= 16) && (lane < 28);
  if (uLane || fLane) {
    const int w = uLane ? lane : lane - 16;
    const int k = uLane ? 1 : 0;
    const int gbase = (k * 12 + w) * 3;
    const int tbase = k * 36 + w * 3;
    const float a0 = gang[gbase + 0] + ttb[tbase + 0];
    const float a1 = gang[gbase + 1] + ttb[tbase + 1];
    const float a2 = gang[gbase + 2] + ttb[tbase + 2];
    const float cx = cosf(0.5f * a0), sx = sinf(0.5f * a0);
    const float cy = cosf(0.5f * a1), sy = sinf(0.5f * a1);
    const float cz = cosf(0.5f * a2), sz = sinf(0.5f * a2);
    const float m00r = cy * cx,   m00i = sy * sx;
    const float m01r = -sy * cx,  m01i = -cy * sx;
    const float m10r = sy * cx,   m10i = -cy * sx;
    const float m11r = cy * cx,   m11i = -sy * sx;
    const float U00r = cz * m00r + sz * m00i, U00i = cz * m00i - sz * m00r;
    const float U01r = cz * m01r + sz * m01i, U01i = cz * m01i - sz * m01r;
    const float U10r = cz * m10r - sz * m10i, U10i = cz * m10i + sz * m10r;
    const float U11r = cz * m11r - sz * m11i, U11i = cz * m11i + sz * m11r;
    if (uLane) {
      c0 = U00r; c1 = U00i; c2 = U01r; c3 = U01i;
    } else {
      const float e = x[(size_t)b * 1024 + w] * 0.5f;
      const float cc = cosf(e), ss = sinf(e);
      c0 = U00r * cc + U01r * ss;  c1 = U00i * cc + U01i * ss;
      c2 = U10r * cc + U11r * ss;  c3 = U10i * cc + U11i * ss;
    }
  }

  // --- P over lane-only wires 0..4 (broadcasts consumed immediately) ---
  const int bwv0 = (lane >> 5) & 1;
  const int bwv1 = ((lane >> 4) ^ (lane >> 3)) & 1;
  const int bwv2 = ((lane >> 3) ^ (lane >> 2)) & 1;
  const int bwv3 = ((lane >> 2) ^ (lane >> 1)) & 1;
  const int bwv4 = ((lane >> 1) ^ lane) & 1;
  const int l0 = lane & 1;

  cpx P;
  {
    const float f0r = __shfl(c0, 16, 64), f0i = __shfl(c1, 16, 64);
    const float f1r = __shfl(c2, 16, 64), f1i = __shfl(c3, 16, 64);
    P = {bwv0 ? f1r : f0r, bwv0 ? f1i : f0i};
  }
  const int bwrest[4] = {bwv1, bwv2, bwv3, bwv4};
#pragma unroll
  for (int w = 1; w < 5; ++w) {
    const float f0r = __shfl(c0, 16 + w, 64), f0i = __shfl(c1, 16 + w, 64);
    const float f1r = __shfl(c2, 16 + w, 64), f1i = __shfl(c3, 16 + w, 64);
    const int bb = bwrest[w - 1];
    P = cmulc(P, {bb ? f1r : f0r, bb ? f1i : f0i});
  }

  // --- PT_hi[8] over wires 5,6,7 (with P folded in) ---
  cpx PT[8];
  {
    cpx F5a, F5b, F6[2], F7[2];
    {
      const cpx q0 = {__shfl(c0, 21, 64), __shfl(c1, 21, 64)};
      const cpx q1 = {__shfl(c2, 21, 64), __shfl(c3, 21, 64)};
      F5a = l0 ? q1 : q0;           // F5[l0 ^ 0]
      F5b = l0 ? q0 : q1;           // F5[l0 ^ 1]
    }
    F6[0] = {__shfl(c0, 22, 64), __shfl(c1, 22, 64)};
    F6[1] = {__shfl(c2, 22, 64), __shfl(c3, 22, 64)};
    F7[0] = {__shfl(c0, 23, 64), __shfl(c1, 23, 64)};
    F7[1] = {__shfl(c2, 23, 64), __shfl(c3, 23, 64)};
    const cpx P5a = cmulc(P, F5a), P5b = cmulc(P, F5b);
    cpx t56[4];
#pragma unroll
    for (int i = 0; i < 4; ++i) {
      const int r5 = i >> 1, r4 = i & 1;
      t56[i] = cmulc(r5 ? P5b : P5a, F6[r5 ^ r4]);
    }
#pragma unroll
    for (int i = 0; i < 8; ++i) {
      const int r4 = (i >> 1) & 1, r3 = i & 1;
      PT[i] = cmulc(t56[i >> 1], F7[r4 ^ r3]);
    }
  }

  // --- T_lo[16] over wires 8..11 ---
  cpx TL[16];
  {
    cpx F8[2], F9[2], F10[2], F11[2];
    F8[0]  = {__shfl(c0, 24, 64), __shfl(c1, 24, 64)};
    F8[1]  = {__shfl(c2, 24, 64), __shfl(c3, 24, 64)};
    F9[0]  = {__shfl(c0, 25, 64), __shfl(c1, 25, 64)};
    F9[1]  = {__shfl(c2, 25, 64), __shfl(c3, 25, 64)};
    F10[0] = {__shfl(c0, 26, 64), __shfl(c1, 26, 64)};
    F10[1] = {__shfl(c2, 26, 64), __shfl(c3, 26, 64)};
    F11[0] = {__shfl(c0, 27, 64), __shfl(c1, 27, 64)};
    F11[1] = {__shfl(c2, 27, 64), __shfl(c3, 27, 64)};
    cpx t10[4];   // (r1,r0)
#pragma unroll
    for (int i = 0; i < 4; ++i) {
      const int r1 = i >> 1, r0 = i & 1;
      t10[i] = cmulc(F10[r1 ^ r0], F11[r0]);
    }
    cpx t9[8];    // (r2,r1,r0)
#pragma unroll
    for (int i = 0; i < 8; ++i) {
      const int r2 = i >> 2, r1 = (i >> 1) & 1;
      t9[i] = cmulc(F9[r2 ^ r1], t10[i & 3]);
    }
#pragma unroll
    for (int i = 0; i < 16; ++i) {
      const int r3 = i >> 3, r2 = (i >> 2) & 1;
      TL[i] = cmulc(F8[r3 ^ r2], t9[i & 7]);
    }
  }

  // --- fill packs: pack j = amps (2j, 2j^3) ---
  f2 R[32], I[32];
#pragma unroll
  for (int j = 0; j < 32; ++j) {
    const cpx Av = PT[(j >> 2) & 7];
    const int il = (2 * j) & 15;
    const f2 Tre = mk2(TL[il].r, TL[il ^ 3].r);
    const f2 Tim = mk2(TL[il].i, TL[il ^ 3].i);
    const f2 Ar = mk2(Av.r, Av.r);
    R[j] = pkfma(mk2(-Av.i, -Av.i), Tim, pkmul(Ar, Tre));
    I[j] = pkfma(mk2(Av.i, Av.i), Tre, pkmul(Ar, Tim));
  }

#define GATE(MASK, ROW, G)                                                  \
  gate_pk<MASK, ROW>(R, I, __shfl(c0, G, 64), __shfl(c1, G, 64),            \
                     __shfl(c2, G, 64), __shfl(c3, G, 64), lane)

  // ---- layer 1 in B basis (layer 0 folded into init) ----
  GATE(0xC00, 0x400, 0);    // w=0   lane xor 0x30
  GATE(0x200, 0xE00, 1);    // w=1   lane xor 0x08
  GATE(0x100, 0xD00, 2);    // w=2   lane xor 0x04
  GATE(0x080, 0xC80, 3);    // w=3   lane xor 0x02
  GATE(0x040, 0xC40, 4);    // w=4   lane xor 0x01
  GATE(0x020, 0xC20, 5);    // w=5   reg 0x20
  GATE(0x010, 0xC10, 6);    // w=6   reg 0x10
  GATE(0x008, 0xC08, 7);    // w=7   reg 8
  GATE(0x004, 0xC04, 8);    // w=8   reg 4
  GATE(0x002, 0xC02, 9);    // w=9   reg 2
  GATE(0x001, 0xC01, 10);   // w=10  reg 1 (half-swap)
  GATE(0xBFF, 0xC00, 11);   // w=11  lane 0x2F + reg 0x3F (half-swap)
#undef GATE

  // ---- measurement: sign(w, s) = parity(MROWS[w] & s), packed ----
  constexpr int MROWS[12] = {0xFFF, 0xA00, 0x700, 0xB80, 0x7C0, 0xBE0,
                             0x7F0, 0xBF8, 0x7FC, 0xBFE, 0x7FF, 0xBFF};
  const f2 Spp = mk2(1.f, 1.f),  Smm = mk2(-1.f, -1.f);
  const f2 Spm = mk2(1.f, -1.f), Smp = mk2(-1.f, 1.f);
  f2 acc2[12];
#pragma unroll
  for (int w = 0; w < 12; ++w) acc2[w] = mk2(0.f, 0.f);
#pragma unroll
  for (int j = 0; j < 32; ++j) {
    const f2 pr2 = pkfma(I[j], I[j], pkmul(R[j], R[j]));
#pragma unroll
    for (int w = 0; w < 12; ++w) {
      const int sl = parity12(MROWS[w] & (2 * j));
      const int sh = sl ^ parity12(MROWS[w] & 3);
      const f2 S = sl ? (sh ? Smm : Smp) : (sh ? Spm : Spp);
      acc2[w] = pkfma(S, pr2, acc2[w]);
    }
  }
#pragma unroll
  for (int w = 0; w < 12; ++w) {
    float v = acc2[w].x + acc2[w].y;
    if (__popc((MROWS[w] >> 6) & lane) & 1) v = -v;
#pragma unroll
    for (int off = 32; off > 0; off >>= 1) v += __shfl_down(v, off, 64);
    if (lane == 0) out[(size_t)b * 12 + w] = v;
  }
}

// ---------------------------------------------------------------------------
extern "C" void kernel_launch(void* const* d_in, const int* in_sizes, int n_in,
                              void* d_out, int out_size, void* d_ws, size_t ws_size,
                              hipStream_t stream) {
  const float* x       = (const float*)d_in[0];
  const float* core0   = (const float*)d_in[1];
  const float* core1   = (const float*)d_in[2];
  const float* tt_bias = (const float*)d_in[3];
  const float* gang    = (const float*)d_in[4];
  float* out = (float*)d_out;
  float* Wt     = (float*)d_ws;                 // 1024*96 floats = 384 KiB
  float* ttout  = (float*)d_ws + 98304;         // 2048*72 floats = 576 KiB

  const int bsz = in_sizes[0] / 1024;  // 2048

  build_w_kernel<<<288, 256, 0, stream>>>(core0, core1, Wt);
  tt_gemm2<<<bsz / 8, 512, 0, stream>>>(x, Wt, tt_bias, ttout);
  vqc_kernel6<<<bsz / 4, 256, 0, stream>>>(x, ttout, gang, out);
}